// Round 1
// baseline (1811.942 us; speedup 1.0000x reference)
//
#include <hip/hip_runtime.h>

// Problem constants
#define NB 2
#define NN 2048
#define NC 768
#define NH 12
#define ND 64
#define ROWS (NB * NN)      // 4096
#define K3C (3 * NC)        // 2304
#define NHEADS (NB * NH)    // 24
#define ATTN_SCALE 0.125f   // 64^-0.5

// ---------------------------------------------------------------------------
// helpers
// ---------------------------------------------------------------------------
__device__ __forceinline__ float qsc(const unsigned* u) {
    // s = max|t|/127 + 1e-8, all in f32 exactly like the jax reference
    return __uint_as_float(*u) / 127.0f + 1e-8f;
}
__device__ __forceinline__ float fq(float t, float s) {
    // jnp.clip(jnp.round(t/s), -127, 127) * s ; rintf == round-half-even
    return fminf(fmaxf(rintf(t / s), -127.0f), 127.0f) * s;
}

// ---------------------------------------------------------------------------
// max |x| reduction (n multiple of 4)
// ---------------------------------------------------------------------------
__global__ __launch_bounds__(256) void maxabs_kernel(const float* __restrict__ x,
                                                     long long n, unsigned* out) {
    float m = 0.0f;
    long long stride4 = (long long)gridDim.x * blockDim.x * 4;
    for (long long j = ((long long)blockIdx.x * blockDim.x + threadIdx.x) * 4; j < n; j += stride4) {
        float4 v = *(const float4*)(x + j);
        m = fmaxf(m, fmaxf(fmaxf(fabsf(v.x), fabsf(v.y)), fmaxf(fabsf(v.z), fabsf(v.w))));
    }
    for (int off = 32; off > 0; off >>= 1) m = fmaxf(m, __shfl_down(m, off, 64));
    __shared__ float sm[4];
    int lane = threadIdx.x & 63, w = threadIdx.x >> 6;
    if (lane == 0) sm[w] = m;
    __syncthreads();
    if (threadIdx.x == 0) {
        float mm = fmaxf(fmaxf(sm[0], sm[1]), fmaxf(sm[2], sm[3]));
        atomicMax(out, __float_as_uint(mm));  // valid: all values >= 0
    }
}

// ---------------------------------------------------------------------------
// elementwise fake-quant (in-place allowed)
// ---------------------------------------------------------------------------
__global__ __launch_bounds__(256) void quant_kernel(const float* in, float* out,
                                                    long long n, const unsigned* umax) {
    float s = qsc(umax);
    long long stride4 = (long long)gridDim.x * blockDim.x * 4;
    for (long long j = ((long long)blockIdx.x * blockDim.x + threadIdx.x) * 4; j < n; j += stride4) {
        float4 v = *(const float4*)(in + j);
        v.x = fq(v.x, s); v.y = fq(v.y, s); v.z = fq(v.z, s); v.w = fq(v.w, s);
        *(float4*)(out + j) = v;
    }
}

// ---------------------------------------------------------------------------
// C[i,j] = sum_k A[i,k] * fq(B[j,k]) + bias[j]   (x @ W^T with W fake-quantized)
// M,N multiples of 64, K multiple of 16. 64x64 tiles, 4x4 micro-tiles.
// ---------------------------------------------------------------------------
__global__ __launch_bounds__(256) void gemm_nt_kernel(const float* __restrict__ A,
                                                      const float* __restrict__ Bw,
                                                      const float* __restrict__ bias,
                                                      float* __restrict__ Cm,
                                                      int M, int Nn, int K,
                                                      const unsigned* __restrict__ uB) {
    __shared__ float As[64][17], Bs[64][17];
    const float sB = qsc(uB);
    const int tid = threadIdx.x, tx = tid & 15, ty = tid >> 4;
    const int row0 = blockIdx.y * 64, col0 = blockIdx.x * 64;
    const int lr = tid >> 2, lc = (tid & 3) << 2;
    float acc[4][4] = {};
    for (int k0 = 0; k0 < K; k0 += 16) {
        float4 av = *(const float4*)(A + (size_t)(row0 + lr) * K + k0 + lc);
        float4 bv = *(const float4*)(Bw + (size_t)(col0 + lr) * K + k0 + lc);
        As[lr][lc] = av.x; As[lr][lc + 1] = av.y; As[lr][lc + 2] = av.z; As[lr][lc + 3] = av.w;
        Bs[lr][lc] = fq(bv.x, sB); Bs[lr][lc + 1] = fq(bv.y, sB);
        Bs[lr][lc + 2] = fq(bv.z, sB); Bs[lr][lc + 3] = fq(bv.w, sB);
        __syncthreads();
#pragma unroll
        for (int kk = 0; kk < 16; ++kk) {
            float a[4], bb[4];
#pragma unroll
            for (int r = 0; r < 4; ++r) a[r] = As[ty * 4 + r][kk];
#pragma unroll
            for (int c = 0; c < 4; ++c) bb[c] = Bs[tx * 4 + c][kk];
#pragma unroll
            for (int r = 0; r < 4; ++r)
#pragma unroll
                for (int c = 0; c < 4; ++c) acc[r][c] = fmaf(a[r], bb[c], acc[r][c]);
        }
        __syncthreads();
    }
#pragma unroll
    for (int r = 0; r < 4; ++r)
#pragma unroll
        for (int c = 0; c < 4; ++c)
            Cm[(size_t)(row0 + ty * 4 + r) * Nn + col0 + tx * 4 + c] =
                acc[r][c] + bias[col0 + tx * 4 + c];
}

// ---------------------------------------------------------------------------
// attention tile helpers
// ---------------------------------------------------------------------------
__device__ __forceinline__ void load_tile64(const float* __restrict__ g, int ld,
                                            float (*sh)[65], int tid) {
    for (int l = tid; l < 1024; l += 256) {
        int r = l >> 4, c = (l & 15) << 2;
        float4 v = *(const float4*)(g + (size_t)r * ld + c);
        sh[r][c] = v.x; sh[r][c + 1] = v.y; sh[r][c + 2] = v.z; sh[r][c + 3] = v.w;
    }
}

__device__ __forceinline__ void dot64(const float (*qs)[65], const float (*ks)[65],
                                      int ty, int tx, float acc[4][4]) {
#pragma unroll 16
    for (int kk = 0; kk < 64; ++kk) {
        float a[4], bb[4];
#pragma unroll
        for (int r = 0; r < 4; ++r) a[r] = qs[ty * 4 + r][kk];
#pragma unroll
        for (int c = 0; c < 4; ++c) bb[c] = ks[tx * 4 + c][kk];
#pragma unroll
        for (int r = 0; r < 4; ++r)
#pragma unroll
            for (int c = 0; c < 4; ++c) acc[r][c] = fmaf(a[r], bb[c], acc[r][c]);
    }
}

// ---------------------------------------------------------------------------
// pass A: global max |attn|
// ---------------------------------------------------------------------------
__global__ __launch_bounds__(256) void attn_max_kernel(const float* __restrict__ qkv,
                                                       unsigned* __restrict__ attnmax) {
    __shared__ float qs[64][65], ks[64][65];
    int hb = blockIdx.z, b = hb / NH, h = hb % NH;
    int i0 = blockIdx.y * 64, j0 = blockIdx.x * 64;
    int tid = threadIdx.x, tx = tid & 15, ty = tid >> 4;
    load_tile64(qkv + (size_t)(b * NN + i0) * K3C + h * ND, K3C, qs, tid);
    load_tile64(qkv + (size_t)(b * NN + j0) * K3C + NC + h * ND, K3C, ks, tid);
    __syncthreads();
    float acc[4][4] = {};
    dot64(qs, ks, ty, tx, acc);
    float m = 0.0f;
#pragma unroll
    for (int r = 0; r < 4; ++r)
#pragma unroll
        for (int c = 0; c < 4; ++c) m = fmaxf(m, fabsf(acc[r][c] * ATTN_SCALE));
    for (int off = 32; off > 0; off >>= 1) m = fmaxf(m, __shfl_down(m, off, 64));
    __shared__ float sm[4];
    int lane = tid & 63, w = tid >> 6;
    if (lane == 0) sm[w] = m;
    __syncthreads();
    if (tid == 0) atomicMax(attnmax, __float_as_uint(fmaxf(fmaxf(sm[0], sm[1]), fmaxf(sm[2], sm[3]))));
}

// ---------------------------------------------------------------------------
// pass B: per-row max M and denom = sum exp(aq - M) of the QUANTIZED scores
// ---------------------------------------------------------------------------
__global__ __launch_bounds__(256) void attn_stats_kernel(const float* __restrict__ qkv,
                                                         const unsigned* __restrict__ attnmax,
                                                         float* __restrict__ Mbuf,
                                                         float* __restrict__ Dbuf) {
    __shared__ float qs[64][65], ks[64][65];
    __shared__ float msh[64][17], ssh[64][17];
    int hb = blockIdx.y, b = hb / NH, h = hb % NH;
    int i0 = blockIdx.x * 64;
    int tid = threadIdx.x, tx = tid & 15, ty = tid >> 4;
    float s = qsc(attnmax);
    load_tile64(qkv + (size_t)(b * NN + i0) * K3C + h * ND, K3C, qs, tid);
    float m[4] = {-INFINITY, -INFINITY, -INFINITY, -INFINITY};
    float sum[4] = {0.f, 0.f, 0.f, 0.f};
    for (int t = 0; t < NN / 64; ++t) {
        load_tile64(qkv + (size_t)(b * NN + t * 64) * K3C + NC + h * ND, K3C, ks, tid);
        __syncthreads();
        float acc[4][4] = {};
        dot64(qs, ks, ty, tx, acc);
#pragma unroll
        for (int r = 0; r < 4; ++r)
#pragma unroll
            for (int c = 0; c < 4; ++c) {
                float aq = fq(acc[r][c] * ATTN_SCALE, s);
                if (aq > m[r]) { sum[r] = sum[r] * expf(m[r] - aq) + 1.0f; m[r] = aq; }
                else           { sum[r] += expf(aq - m[r]); }
            }
        __syncthreads();
    }
#pragma unroll
    for (int r = 0; r < 4; ++r) { msh[ty * 4 + r][tx] = m[r]; ssh[ty * 4 + r][tx] = sum[r]; }
    __syncthreads();
    if (tid < 64) {
        float M = -INFINITY;
        for (int j = 0; j < 16; ++j) M = fmaxf(M, msh[tid][j]);
        float Dn = 0.f;
        for (int j = 0; j < 16; ++j) Dn += ssh[tid][j] * expf(msh[tid][j] - M);
        Mbuf[(size_t)hb * NN + i0 + tid] = M;
        Dbuf[(size_t)hb * NN + i0 + tid] = Dn;
    }
}

// ---------------------------------------------------------------------------
// pass C: recompute scores, log-int-softmax, multiply by V -> O (in [4096,768] layout)
// ---------------------------------------------------------------------------
__global__ __launch_bounds__(256) void attn_pv_kernel(const float* __restrict__ qkv,
                                                      const unsigned* __restrict__ attnmax,
                                                      const float* __restrict__ Mbuf,
                                                      const float* __restrict__ Dbuf,
                                                      float* __restrict__ O) {
    __shared__ float qs[64][65], kvs[64][65], ps[64][65];
    int hb = blockIdx.y, b = hb / NH, h = hb % NH;
    int i0 = blockIdx.x * 64;
    int tid = threadIdx.x, tx = tid & 15, ty = tid >> 4;
    float s = qsc(attnmax);
    load_tile64(qkv + (size_t)(b * NN + i0) * K3C + h * ND, K3C, qs, tid);
    float Mr[4], Lr[4];
#pragma unroll
    for (int r = 0; r < 4; ++r) {
        Mr[r] = Mbuf[(size_t)hb * NN + i0 + ty * 4 + r];
        Lr[r] = log2f(Dbuf[(size_t)hb * NN + i0 + ty * 4 + r]);
    }
    float oacc[4][4] = {};
    for (int t = 0; t < NN / 64; ++t) {
        load_tile64(qkv + (size_t)(b * NN + t * 64) * K3C + NC + h * ND, K3C, kvs, tid);
        __syncthreads();
        float acc[4][4] = {};
        dot64(qs, kvs, ty, tx, acc);
#pragma unroll
        for (int r = 0; r < 4; ++r)
#pragma unroll
            for (int c = 0; c < 4; ++c) {
                float aq = fq(acc[r][c] * ATTN_SCALE, s);
                // -log2(p) = (M - aq)*log2(e) + log2(denom); clip(round(.),0,15); p = 2^-lg
                float tt = (Mr[r] - aq) * 1.4426950408889634f + Lr[r];
                float lg = fminf(fmaxf(rintf(tt), 0.0f), 15.0f);
                ps[ty * 4 + r][tx * 4 + c] = exp2f(-lg);
            }
        __syncthreads();
        load_tile64(qkv + (size_t)(b * NN + t * 64) * K3C + 2 * NC + h * ND, K3C, kvs, tid);
        __syncthreads();
#pragma unroll 8
        for (int j = 0; j < 64; ++j) {
            float p[4], vv[4];
#pragma unroll
            for (int r = 0; r < 4; ++r) p[r] = ps[ty * 4 + r][j];
#pragma unroll
            for (int c = 0; c < 4; ++c) vv[c] = kvs[j][tx * 4 + c];
#pragma unroll
            for (int r = 0; r < 4; ++r)
#pragma unroll
                for (int c = 0; c < 4; ++c) oacc[r][c] = fmaf(p[r], vv[c], oacc[r][c]);
        }
        __syncthreads();
    }
#pragma unroll
    for (int r = 0; r < 4; ++r)
#pragma unroll
        for (int c = 0; c < 4; ++c)
            O[(size_t)(b * NN + i0 + ty * 4 + r) * NC + h * ND + tx * 4 + c] = oacc[r][c];
}

// ---------------------------------------------------------------------------
// launch
// ---------------------------------------------------------------------------
extern "C" void kernel_launch(void* const* d_in, const int* in_sizes, int n_in,
                              void* d_out, int out_size, void* d_ws, size_t ws_size,
                              hipStream_t stream) {
    const float* x      = (const float*)d_in[0];   // [2,2048,768]
    const float* w_qkv  = (const float*)d_in[1];   // [2304,768]
    const float* b_qkv  = (const float*)d_in[2];   // [2304]
    const float* w_out  = (const float*)d_in[3];   // [768,768]
    const float* b_out  = (const float*)d_in[4];   // [768]
    float* out = (float*)d_out;                    // [2,2048,768]

    // workspace layout (~38.2 MB total)
    char* ws = (char*)d_ws;
    unsigned* u = (unsigned*)ws;                   // [0]=wqkv max [1]=wout max [2]=qkv max [3]=attn max [4]=out max
    float* qkv  = (float*)(ws + 256);              // 4096x2304 f32 = 37.75 MB
    float* Mbuf = (float*)(ws + 256 + (size_t)ROWS * K3C * 4);   // 24*2048
    float* Dbuf = Mbuf + (size_t)NHEADS * NN;
    float* out_tmp = qkv;                          // qkv buffer is dead after pass C; reuse

    hipMemsetAsync(u, 0, 64, stream);

    // weight maxima
    maxabs_kernel<<<512, 256, 0, stream>>>(w_qkv, (long long)K3C * NC, u + 0);
    maxabs_kernel<<<512, 256, 0, stream>>>(w_out, (long long)NC * NC, u + 1);

    // qkv = x @ fq(w_qkv)^T + b_qkv
    gemm_nt_kernel<<<dim3(K3C / 64, ROWS / 64), 256, 0, stream>>>(x, w_qkv, b_qkv, qkv,
                                                                  ROWS, K3C, NC, u + 0);
    // qact_qkv
    maxabs_kernel<<<1024, 256, 0, stream>>>(qkv, (long long)ROWS * K3C, u + 2);
    quant_kernel<<<1024, 256, 0, stream>>>(qkv, qkv, (long long)ROWS * K3C, u + 2);

    // attention
    attn_max_kernel<<<dim3(NN / 64, NN / 64, NHEADS), 256, 0, stream>>>(qkv, u + 3);
    attn_stats_kernel<<<dim3(NN / 64, NHEADS), 256, 0, stream>>>(qkv, u + 3, Mbuf, Dbuf);
    attn_pv_kernel<<<dim3(NN / 64, NHEADS), 256, 0, stream>>>(qkv, u + 3, Mbuf, Dbuf, out);

    // out = O @ fq(w_out)^T + b_out  (written to scratch), then qact_out into d_out
    gemm_nt_kernel<<<dim3(NC / 64, ROWS / 64), 256, 0, stream>>>(out, w_out, b_out, out_tmp,
                                                                 ROWS, NC, NC, u + 1);
    maxabs_kernel<<<1024, 256, 0, stream>>>(out_tmp, (long long)ROWS * NC, u + 4);
    quant_kernel<<<1024, 256, 0, stream>>>(out_tmp, out, (long long)ROWS * NC, u + 4);
}

// Round 2
// 990.388 us; speedup vs baseline: 1.8295x; 1.8295x over previous
//
#include <hip/hip_runtime.h>

// Problem constants
#define NB 2
#define NN 2048
#define NC 768
#define NH 12
#define ND 64
#define ROWS (NB * NN)      // 4096
#define K3C (3 * NC)        // 2304
#define NHEADS (NB * NH)    // 24
#define ATTN_SCALE 0.125f   // 64^-0.5

typedef __attribute__((ext_vector_type(8))) short s16x8;
typedef __attribute__((ext_vector_type(4))) float f32x4;

// ---------------------------------------------------------------------------
// helpers
// ---------------------------------------------------------------------------
__device__ __forceinline__ float qsc(const unsigned* u) {
    return __uint_as_float(*u) / 127.0f + 1e-8f;   // s = max|t|/127 + 1e-8
}
__device__ __forceinline__ float fq(float t, float s) {
    return fminf(fmaxf(rintf(t / s), -127.0f), 127.0f) * s;
}
__device__ __forceinline__ float qcode(float t, float s) {   // the integer code as f32
    return fminf(fmaxf(rintf(t / s), -127.0f), 127.0f);
}
__device__ __forceinline__ short bfbits(float f) {           // exact for ints<=127 & powers of 2
    return (short)(__float_as_uint(f) >> 16);
}

// ---------------------------------------------------------------------------
// max |x| reduction (n multiple of 4)
// ---------------------------------------------------------------------------
__global__ __launch_bounds__(256) void maxabs_kernel(const float* __restrict__ x,
                                                     long long n, unsigned* out) {
    float m = 0.0f;
    long long stride4 = (long long)gridDim.x * blockDim.x * 4;
    for (long long j = ((long long)blockIdx.x * blockDim.x + threadIdx.x) * 4; j < n; j += stride4) {
        float4 v = *(const float4*)(x + j);
        m = fmaxf(m, fmaxf(fmaxf(fabsf(v.x), fabsf(v.y)), fmaxf(fabsf(v.z), fabsf(v.w))));
    }
    for (int off = 32; off > 0; off >>= 1) m = fmaxf(m, __shfl_down(m, off, 64));
    __shared__ float sm[4];
    int lane = threadIdx.x & 63, w = threadIdx.x >> 6;
    if (lane == 0) sm[w] = m;
    __syncthreads();
    if (threadIdx.x == 0) {
        float mm = fmaxf(fmaxf(sm[0], sm[1]), fmaxf(sm[2], sm[3]));
        atomicMax(out, __float_as_uint(mm));
    }
}

// ---------------------------------------------------------------------------
// elementwise fake-quant
// ---------------------------------------------------------------------------
__global__ __launch_bounds__(256) void quant_kernel(const float* in, float* out,
                                                    long long n, const unsigned* umax) {
    float s = qsc(umax);
    long long stride4 = (long long)gridDim.x * blockDim.x * 4;
    for (long long j = ((long long)blockIdx.x * blockDim.x + threadIdx.x) * 4; j < n; j += stride4) {
        float4 v = *(const float4*)(in + j);
        v.x = fq(v.x, s); v.y = fq(v.y, s); v.z = fq(v.z, s); v.w = fq(v.w, s);
        *(float4*)(out + j) = v;
    }
}

// ---------------------------------------------------------------------------
// f32 GEMM: C[i,j] = sum_k A[i,k] * fq(B[j,k]) + bias[j]
// ---------------------------------------------------------------------------
__global__ __launch_bounds__(256) void gemm_nt_kernel(const float* __restrict__ A,
                                                      const float* __restrict__ Bw,
                                                      const float* __restrict__ bias,
                                                      float* __restrict__ Cm,
                                                      int M, int Nn, int K,
                                                      const unsigned* __restrict__ uB) {
    __shared__ float As[64][17], Bs[64][17];
    const float sB = qsc(uB);
    const int tid = threadIdx.x, tx = tid & 15, ty = tid >> 4;
    const int row0 = blockIdx.y * 64, col0 = blockIdx.x * 64;
    const int lr = tid >> 2, lc = (tid & 3) << 2;
    float acc[4][4] = {};
    for (int k0 = 0; k0 < K; k0 += 16) {
        float4 av = *(const float4*)(A + (size_t)(row0 + lr) * K + k0 + lc);
        float4 bv = *(const float4*)(Bw + (size_t)(col0 + lr) * K + k0 + lc);
        As[lr][lc] = av.x; As[lr][lc + 1] = av.y; As[lr][lc + 2] = av.z; As[lr][lc + 3] = av.w;
        Bs[lr][lc] = fq(bv.x, sB); Bs[lr][lc + 1] = fq(bv.y, sB);
        Bs[lr][lc + 2] = fq(bv.z, sB); Bs[lr][lc + 3] = fq(bv.w, sB);
        __syncthreads();
#pragma unroll
        for (int kk = 0; kk < 16; ++kk) {
            float a[4], bb[4];
#pragma unroll
            for (int r = 0; r < 4; ++r) a[r] = As[ty * 4 + r][kk];
#pragma unroll
            for (int c = 0; c < 4; ++c) bb[c] = Bs[tx * 4 + c][kk];
#pragma unroll
            for (int r = 0; r < 4; ++r)
#pragma unroll
                for (int c = 0; c < 4; ++c) acc[r][c] = fmaf(a[r], bb[c], acc[r][c]);
        }
        __syncthreads();
    }
#pragma unroll
    for (int r = 0; r < 4; ++r)
#pragma unroll
        for (int c = 0; c < 4; ++c)
            Cm[(size_t)(row0 + ty * 4 + r) * Nn + col0 + tx * 4 + c] =
                acc[r][c] + bias[col0 + tx * 4 + c];
}

// ---------------------------------------------------------------------------
// stage a 64(seq) x 64(d) tile of Q/K codes into swizzled LDS
// elem(row,d) -> lds[row*64 + ((d>>3 ^ (row&7))<<3) + (d&7)]
// ---------------------------------------------------------------------------
__device__ __forceinline__ void stage_rows_tile(const float* __restrict__ src,
                                                ushort* lds, float s, int tid) {
    int row = tid >> 2, c0 = (tid & 3) << 4;
    const float* p = src + (size_t)row * K3C + c0;
    float4 v0 = *(const float4*)(p + 0),  v1 = *(const float4*)(p + 4);
    float4 v2 = *(const float4*)(p + 8),  v3 = *(const float4*)(p + 12);
    s16x8 a, b;
    a[0] = bfbits(qcode(v0.x, s)); a[1] = bfbits(qcode(v0.y, s));
    a[2] = bfbits(qcode(v0.z, s)); a[3] = bfbits(qcode(v0.w, s));
    a[4] = bfbits(qcode(v1.x, s)); a[5] = bfbits(qcode(v1.y, s));
    a[6] = bfbits(qcode(v1.z, s)); a[7] = bfbits(qcode(v1.w, s));
    b[0] = bfbits(qcode(v2.x, s)); b[1] = bfbits(qcode(v2.y, s));
    b[2] = bfbits(qcode(v2.z, s)); b[3] = bfbits(qcode(v2.w, s));
    b[4] = bfbits(qcode(v3.x, s)); b[5] = bfbits(qcode(v3.y, s));
    b[6] = bfbits(qcode(v3.z, s)); b[7] = bfbits(qcode(v3.w, s));
    int u0 = c0 >> 3, r7 = row & 7;
    *(s16x8*)(lds + row * 64 + (((u0    ) ^ r7) << 3)) = a;
    *(s16x8*)(lds + row * 64 + (((u0 + 1) ^ r7) << 3)) = b;
}

// ---------------------------------------------------------------------------
// stage a 64(seq) x 64(d) V tile TRANSPOSED into swizzled LDS: vt[d][j]
// elem(d,j) -> lds[d*64 + ((j>>3 ^ (d&7))<<3) + (j&7)]
// ---------------------------------------------------------------------------
__device__ __forceinline__ void stage_vT_tile(const float* __restrict__ src,
                                              ushort* lds, float s, int tid) {
    int d = tid >> 2, j0 = (tid & 3) << 4;
    const float* p = src + (size_t)j0 * K3C + d;
    s16x8 a, b;
#pragma unroll
    for (int jj = 0; jj < 8; ++jj) a[jj] = bfbits(qcode(p[(size_t)jj * K3C], s));
#pragma unroll
    for (int jj = 0; jj < 8; ++jj) b[jj] = bfbits(qcode(p[(size_t)(8 + jj) * K3C], s));
    int u0 = j0 >> 3, d7 = d & 7;
    *(s16x8*)(lds + d * 64 + (((u0    ) ^ d7) << 3)) = a;
    *(s16x8*)(lds + d * 64 + (((u0 + 1) ^ d7) << 3)) = b;
}

// load Q fragment (ks = K-step 0/1) for wave rows w*16 + (l&15)
__device__ __forceinline__ s16x8 load_q_frag(const float* __restrict__ qp, float s, int ks) {
    float4 f0 = *(const float4*)(qp + ks * 32);
    float4 f1 = *(const float4*)(qp + ks * 32 + 4);
    s16x8 r;
    r[0] = bfbits(qcode(f0.x, s)); r[1] = bfbits(qcode(f0.y, s));
    r[2] = bfbits(qcode(f0.z, s)); r[3] = bfbits(qcode(f0.w, s));
    r[4] = bfbits(qcode(f1.x, s)); r[5] = bfbits(qcode(f1.y, s));
    r[6] = bfbits(qcode(f1.z, s)); r[7] = bfbits(qcode(f1.w, s));
    return r;
}

// ---------------------------------------------------------------------------
// pass A: global max |dot_int| over all (i,j)  (attn = dot * s^2 * SCALE)
// ---------------------------------------------------------------------------
__global__ __launch_bounds__(256) void attn_maxdot_kernel(const float* __restrict__ qkv,
                                                          const unsigned* __restrict__ uq,
                                                          unsigned* __restrict__ umaxdot) {
    __shared__ ushort kt[64 * 64];
    __shared__ float red[4];
    int bh = blockIdx.y, b = bh / NH, h = bh % NH;
    int i0 = blockIdx.x * 64;
    int tid = threadIdx.x, l = tid & 63, w = tid >> 6;
    float s = qsc(uq);

    const float* qp = qkv + (size_t)(b * NN + i0 + w * 16 + (l & 15)) * K3C + h * ND + ((l >> 4) << 3);
    s16x8 qf0 = load_q_frag(qp, s, 0), qf1 = load_q_frag(qp, s, 1);

    const float* kbase = qkv + (size_t)(b * NN) * K3C + NC + h * ND;
    float md = 0.0f;
    for (int st = 0; st < NN / 64; ++st) {
        __syncthreads();
        stage_rows_tile(kbase + (size_t)st * 64 * K3C, kt, s, tid);
        __syncthreads();
#pragma unroll
        for (int jt = 0; jt < 4; ++jt) {
            int row = (jt << 4) + (l & 15);
            f32x4 acc = {0.f, 0.f, 0.f, 0.f};
            s16x8 kf0 = *(s16x8*)(kt + row * 64 + ((((l >> 4)    ) ^ (row & 7)) << 3));
            s16x8 kf1 = *(s16x8*)(kt + row * 64 + ((((l >> 4) + 4) ^ (row & 7)) << 3));
            acc = __builtin_amdgcn_mfma_f32_16x16x32_bf16(qf0, kf0, acc, 0, 0, 0);
            acc = __builtin_amdgcn_mfma_f32_16x16x32_bf16(qf1, kf1, acc, 0, 0, 0);
#pragma unroll
            for (int r = 0; r < 4; ++r) md = fmaxf(md, fabsf(acc[r]));
        }
    }
    for (int m = 1; m < 64; m <<= 1) md = fmaxf(md, __shfl_xor(md, m, 64));
    if (l == 0) red[w] = md;
    __syncthreads();
    if (tid == 0)
        atomicMax(umaxdot, __float_as_uint(fmaxf(fmaxf(red[0], red[1]), fmaxf(red[2], red[3]))));
}

// ---------------------------------------------------------------------------
// fused stats + log-int-softmax + PV.  -log2(p) = log2(U) - aq*log2e, U = sum exp(aq)
// ---------------------------------------------------------------------------
__global__ __launch_bounds__(256) void attn_fused_kernel(const float* __restrict__ qkv,
                                                         const unsigned* __restrict__ uq,
                                                         const unsigned* __restrict__ umaxdot,
                                                         float* __restrict__ O) {
    __shared__ ushort kt[64 * 64];
    __shared__ ushort vt[64 * 64];
    __shared__ ushort ps[4][16 * 64];
    int bh = blockIdx.y, b = bh / NH, h = bh % NH;
    int i0 = blockIdx.x * 64;
    int tid = threadIdx.x, l = tid & 63, w = tid >> 6;
    float s = qsc(uq);
    float c = s * s * ATTN_SCALE;
    float sa = __uint_as_float(*umaxdot) * c / 127.0f + 1e-8f;   // s_attn
    float kk = sa * 1.44269504088896340736f;                      // s_attn * log2(e)

    const float* qp = qkv + (size_t)(b * NN + i0 + w * 16 + (l & 15)) * K3C + h * ND + ((l >> 4) << 3);
    s16x8 qf0 = load_q_frag(qp, s, 0), qf1 = load_q_frag(qp, s, 1);

    const float* kbase = qkv + (size_t)(b * NN) * K3C + NC + h * ND;
    const float* vbase = qkv + (size_t)(b * NN) * K3C + 2 * NC + h * ND;

    // ---- sweep 1: U[r] = sum_j exp(aq) per row ----
    float U[4] = {0.f, 0.f, 0.f, 0.f};
    for (int st = 0; st < NN / 64; ++st) {
        __syncthreads();
        stage_rows_tile(kbase + (size_t)st * 64 * K3C, kt, s, tid);
        __syncthreads();
#pragma unroll
        for (int jt = 0; jt < 4; ++jt) {
            int row = (jt << 4) + (l & 15);
            f32x4 acc = {0.f, 0.f, 0.f, 0.f};
            s16x8 kf0 = *(s16x8*)(kt + row * 64 + ((((l >> 4)    ) ^ (row & 7)) << 3));
            s16x8 kf1 = *(s16x8*)(kt + row * 64 + ((((l >> 4) + 4) ^ (row & 7)) << 3));
            acc = __builtin_amdgcn_mfma_f32_16x16x32_bf16(qf0, kf0, acc, 0, 0, 0);
            acc = __builtin_amdgcn_mfma_f32_16x16x32_bf16(qf1, kf1, acc, 0, 0, 0);
#pragma unroll
            for (int r = 0; r < 4; ++r) {
                float m = qcode(acc[r] * c, sa);
                U[r] += exp2f(kk * m);
            }
        }
    }
#pragma unroll
    for (int r = 0; r < 4; ++r) {
        for (int msk = 1; msk < 16; msk <<= 1) U[r] += __shfl_xor(U[r], msk, 64);
    }
    float lu[4];
#pragma unroll
    for (int r = 0; r < 4; ++r) lu[r] = log2f(U[r]);

    // ---- sweep 2: recompute scores -> p = 2^-lg -> PV ----
    f32x4 oacc[4];
#pragma unroll
    for (int dt = 0; dt < 4; ++dt) oacc[dt] = (f32x4){0.f, 0.f, 0.f, 0.f};
    ushort* myps = (ushort*)ps[w];
    for (int st = 0; st < NN / 64; ++st) {
        __syncthreads();
        stage_rows_tile(kbase + (size_t)st * 64 * K3C, kt, s, tid);
        stage_vT_tile(vbase + (size_t)st * 64 * K3C, vt, s, tid);
        __syncthreads();
#pragma unroll
        for (int jt = 0; jt < 4; ++jt) {
            int row = (jt << 4) + (l & 15);
            f32x4 acc = {0.f, 0.f, 0.f, 0.f};
            s16x8 kf0 = *(s16x8*)(kt + row * 64 + ((((l >> 4)    ) ^ (row & 7)) << 3));
            s16x8 kf1 = *(s16x8*)(kt + row * 64 + ((((l >> 4) + 4) ^ (row & 7)) << 3));
            acc = __builtin_amdgcn_mfma_f32_16x16x32_bf16(qf0, kf0, acc, 0, 0, 0);
            acc = __builtin_amdgcn_mfma_f32_16x16x32_bf16(qf1, kf1, acc, 0, 0, 0);
#pragma unroll
            for (int r = 0; r < 4; ++r) {
                float m = qcode(acc[r] * c, sa);
                float tt = lu[r] - kk * m;
                float lg = fminf(fmaxf(rintf(tt), 0.0f), 15.0f);
                float p = exp2f(-lg);
                int prow = ((l >> 4) << 2) + r;      // 0..15
                int j = (jt << 4) + (l & 15);        // 0..63
                int g = ((j >> 3) ^ (prow & 7)) ^ ((prow >> 3) << 2);
                myps[prow * 64 + (g << 3) + (j & 7)] = (ushort)bfbits(p);
            }
        }
        // PV: O[16 x 64] += P[16 x 64] * V[64 x 64]
#pragma unroll
        for (int kc = 0; kc < 2; ++kc) {
            int prow = l & 15;
            int gA = (((kc << 2) + (l >> 4)) ^ (prow & 7)) ^ ((prow >> 3) << 2);
            s16x8 pf = *(s16x8*)(myps + prow * 64 + (gA << 3));
#pragma unroll
            for (int dt = 0; dt < 4; ++dt) {
                int drow = (dt << 4) + (l & 15);
                s16x8 vf = *(s16x8*)(vt + drow * 64 + ((((kc << 2) + (l >> 4)) ^ (drow & 7)) << 3));
                oacc[dt] = __builtin_amdgcn_mfma_f32_16x16x32_bf16(pf, vf, oacc[dt], 0, 0, 0);
            }
        }
    }
    // write O (scale codes back by s_qkv)
#pragma unroll
    for (int dt = 0; dt < 4; ++dt)
#pragma unroll
        for (int r = 0; r < 4; ++r) {
            int orow = i0 + w * 16 + ((l >> 4) << 2) + r;
            O[(size_t)(b * NN + orow) * NC + h * ND + (dt << 4) + (l & 15)] = s * oacc[dt][r];
        }
}

// ---------------------------------------------------------------------------
// launch
// ---------------------------------------------------------------------------
extern "C" void kernel_launch(void* const* d_in, const int* in_sizes, int n_in,
                              void* d_out, int out_size, void* d_ws, size_t ws_size,
                              hipStream_t stream) {
    const float* x      = (const float*)d_in[0];
    const float* w_qkv  = (const float*)d_in[1];
    const float* b_qkv  = (const float*)d_in[2];
    const float* w_out  = (const float*)d_in[3];
    const float* b_out  = (const float*)d_in[4];
    float* out = (float*)d_out;

    char* ws = (char*)d_ws;
    unsigned* u = (unsigned*)ws;        // 0:wqkv 1:wout 2:qkv 3:maxdot 4:out
    float* qkv = (float*)(ws + 256);    // 4096x2304 f32 = 37.75 MB
    float* out_tmp = qkv;               // reuse after attention

    hipMemsetAsync(u, 0, 64, stream);

    maxabs_kernel<<<512, 256, 0, stream>>>(w_qkv, (long long)K3C * NC, u + 0);
    maxabs_kernel<<<512, 256, 0, stream>>>(w_out, (long long)NC * NC, u + 1);

    gemm_nt_kernel<<<dim3(K3C / 64, ROWS / 64), 256, 0, stream>>>(x, w_qkv, b_qkv, qkv,
                                                                  ROWS, K3C, NC, u + 0);
    maxabs_kernel<<<1024, 256, 0, stream>>>(qkv, (long long)ROWS * K3C, u + 2);

    attn_maxdot_kernel<<<dim3(NN / 64, NHEADS), 256, 0, stream>>>(qkv, u + 2, u + 3);
    attn_fused_kernel<<<dim3(NN / 64, NHEADS), 256, 0, stream>>>(qkv, u + 2, u + 3, out);

    gemm_nt_kernel<<<dim3(NC / 64, ROWS / 64), 256, 0, stream>>>(out, w_out, b_out, out_tmp,
                                                                 ROWS, NC, NC, u + 1);
    maxabs_kernel<<<1024, 256, 0, stream>>>(out_tmp, (long long)ROWS * NC, u + 4);
    quant_kernel<<<1024, 256, 0, stream>>>(out_tmp, out, (long long)ROWS * NC, u + 4);
}

// Round 3
// 708.906 us; speedup vs baseline: 2.5560x; 1.3971x over previous
//
#include <hip/hip_runtime.h>

// Problem constants
#define NB 2
#define NN 2048
#define NC 768
#define NH 12
#define ND 64
#define ROWS (NB * NN)      // 4096
#define K3C (3 * NC)        // 2304
#define NHEADS (NB * NH)    // 24
#define ATTN_SCALE 0.125f   // 64^-0.5

typedef __attribute__((ext_vector_type(8))) short s16x8;
typedef __attribute__((ext_vector_type(4))) float f32x4;

// ---------------------------------------------------------------------------
// helpers
// ---------------------------------------------------------------------------
__device__ __forceinline__ float qsc(const unsigned* u) {
    return __uint_as_float(*u) / 127.0f + 1e-8f;   // s = max|t|/127 + 1e-8
}
__device__ __forceinline__ float fq(float t, float s) {
    return fminf(fmaxf(rintf(t / s), -127.0f), 127.0f) * s;
}
__device__ __forceinline__ float qcode(float t, float s) {   // integer code as f32 (exact div)
    return fminf(fmaxf(rintf(t / s), -127.0f), 127.0f);
}
__device__ __forceinline__ short bfbits(float f) {           // exact for ints<=127 & pow2
    return (short)(__float_as_uint(f) >> 16);
}

// ---------------------------------------------------------------------------
// max |x| reduction
// ---------------------------------------------------------------------------
__global__ __launch_bounds__(256) void maxabs_kernel(const float* __restrict__ x,
                                                     long long n, unsigned* out) {
    float m = 0.0f;
    long long stride4 = (long long)gridDim.x * blockDim.x * 4;
    for (long long j = ((long long)blockIdx.x * blockDim.x + threadIdx.x) * 4; j < n; j += stride4) {
        float4 v = *(const float4*)(x + j);
        m = fmaxf(m, fmaxf(fmaxf(fabsf(v.x), fabsf(v.y)), fmaxf(fabsf(v.z), fabsf(v.w))));
    }
    for (int off = 32; off > 0; off >>= 1) m = fmaxf(m, __shfl_down(m, off, 64));
    __shared__ float sm[4];
    int lane = threadIdx.x & 63, w = threadIdx.x >> 6;
    if (lane == 0) sm[w] = m;
    __syncthreads();
    if (threadIdx.x == 0) {
        float mm = fmaxf(fmaxf(sm[0], sm[1]), fmaxf(sm[2], sm[3]));
        atomicMax(out, __float_as_uint(mm));
    }
}

// ---------------------------------------------------------------------------
// elementwise fake-quant
// ---------------------------------------------------------------------------
__global__ __launch_bounds__(256) void quant_kernel(const float* in, float* out,
                                                    long long n, const unsigned* umax) {
    float s = qsc(umax);
    long long stride4 = (long long)gridDim.x * blockDim.x * 4;
    for (long long j = ((long long)blockIdx.x * blockDim.x + threadIdx.x) * 4; j < n; j += stride4) {
        float4 v = *(const float4*)(in + j);
        v.x = fq(v.x, s); v.y = fq(v.y, s); v.z = fq(v.z, s); v.w = fq(v.w, s);
        *(float4*)(out + j) = v;
    }
}

// ---------------------------------------------------------------------------
// qkv f32 -> integer codes stored as bf16 bits (exact division, bit-identical
// to the reference's quant decisions). codes are ints in [-127,127].
// ---------------------------------------------------------------------------
__global__ __launch_bounds__(256) void quantcodes_kernel(const float* __restrict__ in,
                                                         ushort* __restrict__ codes,
                                                         long long n,
                                                         const unsigned* __restrict__ umax) {
    float s = qsc(umax);
    long long stride8 = (long long)gridDim.x * blockDim.x * 8;
    for (long long j = ((long long)blockIdx.x * blockDim.x + threadIdx.x) * 8; j < n; j += stride8) {
        float4 a = *(const float4*)(in + j);
        float4 b = *(const float4*)(in + j + 4);
        s16x8 o;
        o[0] = bfbits(qcode(a.x, s)); o[1] = bfbits(qcode(a.y, s));
        o[2] = bfbits(qcode(a.z, s)); o[3] = bfbits(qcode(a.w, s));
        o[4] = bfbits(qcode(b.x, s)); o[5] = bfbits(qcode(b.y, s));
        o[6] = bfbits(qcode(b.z, s)); o[7] = bfbits(qcode(b.w, s));
        *(s16x8*)(codes + j) = o;
    }
}

// ---------------------------------------------------------------------------
// f32 GEMM: C[i,j] = sum_k A[i,k] * fq(B[j,k]) + bias[j]
// ---------------------------------------------------------------------------
__global__ __launch_bounds__(256) void gemm_nt_kernel(const float* __restrict__ A,
                                                      const float* __restrict__ Bw,
                                                      const float* __restrict__ bias,
                                                      float* __restrict__ Cm,
                                                      int M, int Nn, int K,
                                                      const unsigned* __restrict__ uB) {
    __shared__ float As[64][17], Bs[64][17];
    const float sB = qsc(uB);
    const int tid = threadIdx.x, tx = tid & 15, ty = tid >> 4;
    const int row0 = blockIdx.y * 64, col0 = blockIdx.x * 64;
    const int lr = tid >> 2, lc = (tid & 3) << 2;
    float acc[4][4] = {};
    for (int k0 = 0; k0 < K; k0 += 16) {
        float4 av = *(const float4*)(A + (size_t)(row0 + lr) * K + k0 + lc);
        float4 bv = *(const float4*)(Bw + (size_t)(col0 + lr) * K + k0 + lc);
        As[lr][lc] = av.x; As[lr][lc + 1] = av.y; As[lr][lc + 2] = av.z; As[lr][lc + 3] = av.w;
        Bs[lr][lc] = fq(bv.x, sB); Bs[lr][lc + 1] = fq(bv.y, sB);
        Bs[lr][lc + 2] = fq(bv.z, sB); Bs[lr][lc + 3] = fq(bv.w, sB);
        __syncthreads();
#pragma unroll
        for (int kk = 0; kk < 16; ++kk) {
            float a[4], bb[4];
#pragma unroll
            for (int r = 0; r < 4; ++r) a[r] = As[ty * 4 + r][kk];
#pragma unroll
            for (int c = 0; c < 4; ++c) bb[c] = Bs[tx * 4 + c][kk];
#pragma unroll
            for (int r = 0; r < 4; ++r)
#pragma unroll
                for (int c = 0; c < 4; ++c) acc[r][c] = fmaf(a[r], bb[c], acc[r][c]);
        }
        __syncthreads();
    }
#pragma unroll
    for (int r = 0; r < 4; ++r)
#pragma unroll
        for (int c = 0; c < 4; ++c)
            Cm[(size_t)(row0 + ty * 4 + r) * Nn + col0 + tx * 4 + c] =
                acc[r][c] + bias[col0 + tx * 4 + c];
}

// ---------------------------------------------------------------------------
// stage a 64(seq) x 64(d) tile of codes into XOR-swizzled LDS (pure copy).
// LDS[row][g] holds global col-group g^ (row&7); frag reads XOR the same way.
// ---------------------------------------------------------------------------
__device__ __forceinline__ void stage_k_tile(const ushort* __restrict__ src,  // tile row 0
                                             ushort* lds, int tid) {
    int row = tid >> 2, u0 = (tid & 3) << 1, r7 = row & 7;
    const ushort* p = src + (size_t)row * K3C + (u0 << 3);
    s16x8 t0 = *(const s16x8*)(p);
    s16x8 t1 = *(const s16x8*)(p + 8);
    *(s16x8*)(lds + row * 64 + ((u0 ^ r7) << 3)) = t0;
    *(s16x8*)(lds + row * 64 + (((u0 | 1) ^ r7) << 3)) = t1;
}

// stage a 64(seq) x 64(d) V tile TRANSPOSED into swizzled LDS: vt[d][j]
__device__ __forceinline__ void stage_vT_tile(const ushort* __restrict__ src,
                                              ushort* lds, int tid) {
    int d = tid >> 2, j0 = (tid & 3) << 4;
    const ushort* p = src + (size_t)j0 * K3C + d;
    s16x8 a, b;
#pragma unroll
    for (int jj = 0; jj < 8; ++jj) a[jj] = (short)p[(size_t)jj * K3C];
#pragma unroll
    for (int jj = 0; jj < 8; ++jj) b[jj] = (short)p[(size_t)(8 + jj) * K3C];
    int u0 = j0 >> 3, d7 = d & 7;
    *(s16x8*)(lds + d * 64 + ((u0 ^ d7) << 3)) = a;
    *(s16x8*)(lds + d * 64 + (((u0 | 1) ^ d7) << 3)) = b;
}

// ---------------------------------------------------------------------------
// pass A: global max |dot_int| (codes are the integer values; dot is exact)
// ---------------------------------------------------------------------------
__global__ __launch_bounds__(256) void attn_maxdot_kernel(const ushort* __restrict__ codes,
                                                          unsigned* __restrict__ umaxdot) {
    __shared__ ushort kt[64 * 64];
    __shared__ float red[4];
    int bh = blockIdx.y, b = bh / NH, h = bh % NH;
    int i0 = blockIdx.x * 64;
    int tid = threadIdx.x, l = tid & 63, w = tid >> 6;

    const ushort* qp = codes + (size_t)(b * NN + i0 + w * 16 + (l & 15)) * K3C + h * ND + ((l >> 4) << 3);
    s16x8 qf0 = *(const s16x8*)(qp);
    s16x8 qf1 = *(const s16x8*)(qp + 32);

    const ushort* kbase = codes + (size_t)(b * NN) * K3C + NC + h * ND;
    float md = 0.0f;
    for (int st = 0; st < NN / 64; ++st) {
        __syncthreads();
        stage_k_tile(kbase + (size_t)st * 64 * K3C, kt, tid);
        __syncthreads();
#pragma unroll
        for (int jt = 0; jt < 4; ++jt) {
            int row = (jt << 4) + (l & 15);
            f32x4 acc = {0.f, 0.f, 0.f, 0.f};
            s16x8 kf0 = *(s16x8*)(kt + row * 64 + ((((l >> 4)    ) ^ (row & 7)) << 3));
            s16x8 kf1 = *(s16x8*)(kt + row * 64 + ((((l >> 4) + 4) ^ (row & 7)) << 3));
            acc = __builtin_amdgcn_mfma_f32_16x16x32_bf16(qf0, kf0, acc, 0, 0, 0);
            acc = __builtin_amdgcn_mfma_f32_16x16x32_bf16(qf1, kf1, acc, 0, 0, 0);
#pragma unroll
            for (int r = 0; r < 4; ++r) md = fmaxf(md, fabsf(acc[r]));
        }
    }
    for (int m = 1; m < 64; m <<= 1) md = fmaxf(md, __shfl_xor(md, m, 64));
    if (l == 0) red[w] = md;
    __syncthreads();
    if (tid == 0)
        atomicMax(umaxdot, __float_as_uint(fmaxf(fmaxf(red[0], red[1]), fmaxf(red[2], red[3]))));
}

// ---------------------------------------------------------------------------
// fused log-int-softmax + PV.  -log2(p) = log2(U) - aq*log2e, U = sum exp(aq)
// ---------------------------------------------------------------------------
__global__ __launch_bounds__(256) void attn_fused_kernel(const ushort* __restrict__ codes,
                                                         const unsigned* __restrict__ uq,
                                                         const unsigned* __restrict__ umaxdot,
                                                         float* __restrict__ O) {
    __shared__ ushort kt[64 * 64];
    __shared__ ushort vt[64 * 64];
    __shared__ ushort ps[4][16 * 64];
    int bh = blockIdx.y, b = bh / NH, h = bh % NH;
    int i0 = blockIdx.x * 64;
    int tid = threadIdx.x, l = tid & 63, w = tid >> 6;
    float s = qsc(uq);
    float c = s * s * ATTN_SCALE;
    float sa = __uint_as_float(*umaxdot) * c / 127.0f + 1e-8f;   // s_attn
    float rr = c / sa;                                           // dot -> attn-code
    float kk = sa * 1.44269504088896340736f;                     // s_attn * log2(e)

    const ushort* qp = codes + (size_t)(b * NN + i0 + w * 16 + (l & 15)) * K3C + h * ND + ((l >> 4) << 3);
    s16x8 qf0 = *(const s16x8*)(qp);
    s16x8 qf1 = *(const s16x8*)(qp + 32);

    const ushort* kbase = codes + (size_t)(b * NN) * K3C + NC + h * ND;
    const ushort* vbase = codes + (size_t)(b * NN) * K3C + 2 * NC + h * ND;

    // ---- sweep 1: U[r] = sum_j exp(aq) per row ----
    float U[4] = {0.f, 0.f, 0.f, 0.f};
    for (int st = 0; st < NN / 64; ++st) {
        __syncthreads();
        stage_k_tile(kbase + (size_t)st * 64 * K3C, kt, tid);
        __syncthreads();
#pragma unroll
        for (int jt = 0; jt < 4; ++jt) {
            int row = (jt << 4) + (l & 15);
            f32x4 acc = {0.f, 0.f, 0.f, 0.f};
            s16x8 kf0 = *(s16x8*)(kt + row * 64 + ((((l >> 4)    ) ^ (row & 7)) << 3));
            s16x8 kf1 = *(s16x8*)(kt + row * 64 + ((((l >> 4) + 4) ^ (row & 7)) << 3));
            acc = __builtin_amdgcn_mfma_f32_16x16x32_bf16(qf0, kf0, acc, 0, 0, 0);
            acc = __builtin_amdgcn_mfma_f32_16x16x32_bf16(qf1, kf1, acc, 0, 0, 0);
#pragma unroll
            for (int r = 0; r < 4; ++r) {
                float m = rintf(acc[r] * rr);          // |dot*rr| < 127.0001 -> no clamp
                U[r] += exp2f(kk * m);
            }
        }
    }
#pragma unroll
    for (int r = 0; r < 4; ++r) {
        for (int msk = 1; msk < 16; msk <<= 1) U[r] += __shfl_xor(U[r], msk, 64);
    }
    float lu[4];
#pragma unroll
    for (int r = 0; r < 4; ++r) lu[r] = log2f(U[r]);

    // ---- sweep 2: recompute scores -> p = 2^-lg -> PV ----
    f32x4 oacc[4];
#pragma unroll
    for (int dt = 0; dt < 4; ++dt) oacc[dt] = (f32x4){0.f, 0.f, 0.f, 0.f};
    ushort* myps = (ushort*)ps[w];
    for (int st = 0; st < NN / 64; ++st) {
        __syncthreads();
        stage_k_tile(kbase + (size_t)st * 64 * K3C, kt, tid);
        stage_vT_tile(vbase + (size_t)st * 64 * K3C, vt, tid);
        __syncthreads();
#pragma unroll
        for (int jt = 0; jt < 4; ++jt) {
            int row = (jt << 4) + (l & 15);
            f32x4 acc = {0.f, 0.f, 0.f, 0.f};
            s16x8 kf0 = *(s16x8*)(kt + row * 64 + ((((l >> 4)    ) ^ (row & 7)) << 3));
            s16x8 kf1 = *(s16x8*)(kt + row * 64 + ((((l >> 4) + 4) ^ (row & 7)) << 3));
            acc = __builtin_amdgcn_mfma_f32_16x16x32_bf16(qf0, kf0, acc, 0, 0, 0);
            acc = __builtin_amdgcn_mfma_f32_16x16x32_bf16(qf1, kf1, acc, 0, 0, 0);
#pragma unroll
            for (int r = 0; r < 4; ++r) {
                float m = rintf(acc[r] * rr);
                float tt = lu[r] - kk * m;
                float lg = fminf(fmaxf(rintf(tt), 0.0f), 15.0f);
                int lgi = (int)lg;
                ushort pbits = (ushort)((127 - lgi) << 7);   // bf16 bits of 2^-lg
                int prow = ((l >> 4) << 2) + r;              // 0..15
                int j = (jt << 4) + (l & 15);                // 0..63
                int g = ((j >> 3) ^ (prow & 7)) ^ ((prow >> 3) << 2);
                myps[prow * 64 + (g << 3) + (j & 7)] = pbits;
            }
        }
        // PV: O[16 x 64] += P[16 x 64] * V[64 x 64]
#pragma unroll
        for (int kc = 0; kc < 2; ++kc) {
            int prow = l & 15;
            int gA = (((kc << 2) + (l >> 4)) ^ (prow & 7)) ^ ((prow >> 3) << 2);
            s16x8 pf = *(s16x8*)(myps + prow * 64 + (gA << 3));
#pragma unroll
            for (int dt = 0; dt < 4; ++dt) {
                int drow = (dt << 4) + (l & 15);
                s16x8 vf = *(s16x8*)(vt + drow * 64 + ((((kc << 2) + (l >> 4)) ^ (drow & 7)) << 3));
                oacc[dt] = __builtin_amdgcn_mfma_f32_16x16x32_bf16(pf, vf, oacc[dt], 0, 0, 0);
            }
        }
    }
    // write O (scale codes back by s_qkv)
#pragma unroll
    for (int dt = 0; dt < 4; ++dt)
#pragma unroll
        for (int r = 0; r < 4; ++r) {
            int orow = i0 + w * 16 + ((l >> 4) << 2) + r;
            O[(size_t)(b * NN + orow) * NC + h * ND + (dt << 4) + (l & 15)] = s * oacc[dt][r];
        }
}

// ---------------------------------------------------------------------------
// launch
// ---------------------------------------------------------------------------
extern "C" void kernel_launch(void* const* d_in, const int* in_sizes, int n_in,
                              void* d_out, int out_size, void* d_ws, size_t ws_size,
                              hipStream_t stream) {
    const float* x      = (const float*)d_in[0];
    const float* w_qkv  = (const float*)d_in[1];
    const float* b_qkv  = (const float*)d_in[2];
    const float* w_out  = (const float*)d_in[3];
    const float* b_out  = (const float*)d_in[4];
    float* out = (float*)d_out;

    char* ws = (char*)d_ws;
    unsigned* u = (unsigned*)ws;                 // 0:wqkv 1:wout 2:qkv 3:maxdot 4:out
    float* qkv = (float*)(ws + 256);             // 4096x2304 f32 = 37.75 MB
    ushort* codes = (ushort*)(ws + 256 + (size_t)ROWS * K3C * 4);  // 18.9 MB bf16 codes
    float* out_tmp = qkv;                        // reuse after attention

    hipMemsetAsync(u, 0, 64, stream);

    maxabs_kernel<<<512, 256, 0, stream>>>(w_qkv, (long long)K3C * NC, u + 0);
    maxabs_kernel<<<512, 256, 0, stream>>>(w_out, (long long)NC * NC, u + 1);

    gemm_nt_kernel<<<dim3(K3C / 64, ROWS / 64), 256, 0, stream>>>(x, w_qkv, b_qkv, qkv,
                                                                  ROWS, K3C, NC, u + 0);
    maxabs_kernel<<<1024, 256, 0, stream>>>(qkv, (long long)ROWS * K3C, u + 2);
    quantcodes_kernel<<<2048, 256, 0, stream>>>(qkv, codes, (long long)ROWS * K3C, u + 2);

    attn_maxdot_kernel<<<dim3(NN / 64, NHEADS), 256, 0, stream>>>(codes, u + 3);
    attn_fused_kernel<<<dim3(NN / 64, NHEADS), 256, 0, stream>>>(codes, u + 2, u + 3, out);

    gemm_nt_kernel<<<dim3(NC / 64, ROWS / 64), 256, 0, stream>>>(out, w_out, b_out, out_tmp,
                                                                 ROWS, NC, NC, u + 1);
    maxabs_kernel<<<1024, 256, 0, stream>>>(out_tmp, (long long)ROWS * NC, u + 4);
    quant_kernel<<<1024, 256, 0, stream>>>(out_tmp, out, (long long)ROWS * NC, u + 4);
}

// Round 5
// 424.221 us; speedup vs baseline: 4.2712x; 1.6711x over previous
//
#include <hip/hip_runtime.h>

// Problem constants
#define NB 2
#define NN 2048
#define NC 768
#define NH 12
#define ND 64
#define ROWS (NB * NN)      // 4096
#define K3C (3 * NC)        // 2304
#define NHEADS (NB * NH)    // 24
#define ATTN_SCALE 0.125f   // 64^-0.5

typedef __attribute__((ext_vector_type(8))) short s16x8;
typedef __attribute__((ext_vector_type(4))) float f32x4;

// ---------------------------------------------------------------------------
// helpers
// ---------------------------------------------------------------------------
__device__ __forceinline__ float qsc(const unsigned* u) {
    return __uint_as_float(*u) / 127.0f + 1e-8f;   // s = max|t|/127 + 1e-8
}
__device__ __forceinline__ float fq(float t, float s) {
    return fminf(fmaxf(rintf(t / s), -127.0f), 127.0f) * s;
}
__device__ __forceinline__ float qcode(float t, float s) {   // integer code as f32 (exact div)
    return fminf(fmaxf(rintf(t / s), -127.0f), 127.0f);
}
__device__ __forceinline__ short bfbits(float f) {           // exact for ints<=127 & pow2
    return (short)(__float_as_uint(f) >> 16);
}
__device__ __forceinline__ ushort bf_rne(float x) {          // round-to-nearest-even bf16
    unsigned u = __float_as_uint(x);
    return (ushort)((u + 0x7fffu + ((u >> 16) & 1u)) >> 16);
}

// ---------------------------------------------------------------------------
// max |x| reduction
// ---------------------------------------------------------------------------
__global__ __launch_bounds__(256) void maxabs_kernel(const float* __restrict__ x,
                                                     long long n, unsigned* out) {
    float m = 0.0f;
    long long stride4 = (long long)gridDim.x * blockDim.x * 4;
    for (long long j = ((long long)blockIdx.x * blockDim.x + threadIdx.x) * 4; j < n; j += stride4) {
        float4 v = *(const float4*)(x + j);
        m = fmaxf(m, fmaxf(fmaxf(fabsf(v.x), fabsf(v.y)), fmaxf(fabsf(v.z), fabsf(v.w))));
    }
    for (int off = 32; off > 0; off >>= 1) m = fmaxf(m, __shfl_down(m, off, 64));
    __shared__ float sm[4];
    int lane = threadIdx.x & 63, w = threadIdx.x >> 6;
    if (lane == 0) sm[w] = m;
    __syncthreads();
    if (threadIdx.x == 0) {
        float mm = fmaxf(fmaxf(sm[0], sm[1]), fmaxf(sm[2], sm[3]));
        atomicMax(out, __float_as_uint(mm));
    }
}

// ---------------------------------------------------------------------------
// elementwise fake-quant
// ---------------------------------------------------------------------------
__global__ __launch_bounds__(256) void quant_kernel(const float* in, float* out,
                                                    long long n, const unsigned* umax) {
    float s = qsc(umax);
    long long stride4 = (long long)gridDim.x * blockDim.x * 4;
    for (long long j = ((long long)blockIdx.x * blockDim.x + threadIdx.x) * 4; j < n; j += stride4) {
        float4 v = *(const float4*)(in + j);
        v.x = fq(v.x, s); v.y = fq(v.y, s); v.z = fq(v.z, s); v.w = fq(v.w, s);
        *(float4*)(out + j) = v;
    }
}

// ---------------------------------------------------------------------------
// f32 -> integer codes stored as bf16 bits (exact division, bit-identical
// to the reference's quant decisions). codes are ints in [-127,127].
// ---------------------------------------------------------------------------
__global__ __launch_bounds__(256) void quantcodes_kernel(const float* __restrict__ in,
                                                         ushort* __restrict__ codes,
                                                         long long n,
                                                         const unsigned* __restrict__ umax) {
    float s = qsc(umax);
    long long stride8 = (long long)gridDim.x * blockDim.x * 8;
    for (long long j = ((long long)blockIdx.x * blockDim.x + threadIdx.x) * 8; j < n; j += stride8) {
        float4 a = *(const float4*)(in + j);
        float4 b = *(const float4*)(in + j + 4);
        s16x8 o;
        o[0] = bfbits(qcode(a.x, s)); o[1] = bfbits(qcode(a.y, s));
        o[2] = bfbits(qcode(a.z, s)); o[3] = bfbits(qcode(a.w, s));
        o[4] = bfbits(qcode(b.x, s)); o[5] = bfbits(qcode(b.y, s));
        o[6] = bfbits(qcode(b.z, s)); o[7] = bfbits(qcode(b.w, s));
        *(s16x8*)(codes + j) = o;
    }
}

// ---------------------------------------------------------------------------
// f32 [R][768] -> 3-term bf16 split stored [R][2304]: hi | mid | lo planes.
// x = hi + mid + lo with residual <= 2^-27 |x|  (far below f32 order noise).
// ---------------------------------------------------------------------------
__global__ __launch_bounds__(256) void split3_kernel(const float* __restrict__ in,
                                                     ushort* __restrict__ xs,
                                                     long long n) {
    long long stride8 = (long long)gridDim.x * blockDim.x * 8;
    for (long long j = ((long long)blockIdx.x * blockDim.x + threadIdx.x) * 8; j < n; j += stride8) {
        long long row = j / NC, col = j % NC;
        s16x8 h, m, l;
#pragma unroll
        for (int i = 0; i < 8; i += 4) {
            float4 v = *(const float4*)(in + j + i);
            float vv[4] = {v.x, v.y, v.z, v.w};
#pragma unroll
            for (int t = 0; t < 4; ++t) {
                ushort hb = bf_rne(vv[t]);
                float hf = __uint_as_float(((unsigned)hb) << 16);
                float r1 = vv[t] - hf;
                ushort mb = bf_rne(r1);
                float mf = __uint_as_float(((unsigned)mb) << 16);
                h[i + t] = (short)hb;
                m[i + t] = (short)mb;
                l[i + t] = (short)bf_rne(r1 - mf);
            }
        }
        ushort* dst = xs + row * (3 * NC) + col;
        *(s16x8*)(dst) = h;
        *(s16x8*)(dst + NC) = m;
        *(s16x8*)(dst + 2 * NC) = l;
    }
}

// ---------------------------------------------------------------------------
// MFMA GEMM: C[i,j] = sB * sum_k (hi+mid+lo)_ik * n_jk + bias[j]
// As: [4096][2304] bf16 hi|mid|lo.  Bc: [Nn][768] bf16 integer codes.
// 128x128 tile, 4 waves (2x2), BK=64, 16x16x32 bf16 MFMA. LDS 64 KB.
// ---------------------------------------------------------------------------
__global__ __launch_bounds__(256) void gemm3_mfma_kernel(const ushort* __restrict__ As,
                                                         const ushort* __restrict__ Bc,
                                                         const float* __restrict__ bias,
                                                         float* __restrict__ Cm, int Nn,
                                                         const unsigned* __restrict__ uB) {
    __shared__ ushort ah[128 * 64], am[128 * 64], al[128 * 64], bs[128 * 64];
    const float sB = qsc(uB);
    const int tid = threadIdx.x, l = tid & 63, w = tid >> 6;
    const int row0 = blockIdx.y * 128, col0 = blockIdx.x * 128;
    const int wr = w >> 1, wc = w & 1;
    f32x4 acc[4][4];
#pragma unroll
    for (int m = 0; m < 4; ++m)
#pragma unroll
        for (int n = 0; n < 4; ++n) acc[m][n] = (f32x4){0.f, 0.f, 0.f, 0.f};

    const int sr = tid >> 1, sh = (tid & 1) << 5;   // stage: row 0..127, k-off 0/32
    const int su = sh >> 3, s7 = sr & 7;

    for (int k0 = 0; k0 < NC; k0 += 64) {
        __syncthreads();
        {   // A hi/mid/lo tiles
            const ushort* ph = As + (size_t)(row0 + sr) * (3 * NC) + k0 + sh;
            ushort* dsts[3] = {ah + sr * 64, am + sr * 64, al + sr * 64};
#pragma unroll
            for (int pl = 0; pl < 3; ++pl) {
                const ushort* p = ph + pl * NC;
                s16x8 t0 = *(const s16x8*)(p),      t1 = *(const s16x8*)(p + 8);
                s16x8 t2 = *(const s16x8*)(p + 16), t3 = *(const s16x8*)(p + 24);
                ushort* d = dsts[pl];
                *(s16x8*)(d + (((su | 0) ^ s7) << 3)) = t0;
                *(s16x8*)(d + (((su | 1) ^ s7) << 3)) = t1;
                *(s16x8*)(d + (((su | 2) ^ s7) << 3)) = t2;
                *(s16x8*)(d + (((su | 3) ^ s7) << 3)) = t3;
            }
            // B tile
            const ushort* pb = Bc + (size_t)(col0 + sr) * NC + k0 + sh;
            s16x8 b0 = *(const s16x8*)(pb),      b1 = *(const s16x8*)(pb + 8);
            s16x8 b2 = *(const s16x8*)(pb + 16), b3 = *(const s16x8*)(pb + 24);
            ushort* brow = bs + sr * 64;
            *(s16x8*)(brow + (((su | 0) ^ s7) << 3)) = b0;
            *(s16x8*)(brow + (((su | 1) ^ s7) << 3)) = b1;
            *(s16x8*)(brow + (((su | 2) ^ s7) << 3)) = b2;
            *(s16x8*)(brow + (((su | 3) ^ s7) << 3)) = b3;
        }
        __syncthreads();
#pragma unroll
        for (int ks = 0; ks < 2; ++ks) {
            s16x8 bf[4];
#pragma unroll
            for (int n = 0; n < 4; ++n) {
                int br = wc * 64 + n * 16 + (l & 15);
                bf[n] = *(s16x8*)(bs + br * 64 + ((((ks << 2) + (l >> 4)) ^ (br & 7)) << 3));
            }
#pragma unroll
            for (int m = 0; m < 4; ++m) {
                int ar = wr * 64 + m * 16 + (l & 15);
                int ao = ar * 64 + ((((ks << 2) + (l >> 4)) ^ (ar & 7)) << 3);
                s16x8 af = *(s16x8*)(ah + ao);
                s16x8 mf_ = *(s16x8*)(am + ao);
                s16x8 ef = *(s16x8*)(al + ao);
#pragma unroll
                for (int n = 0; n < 4; ++n) {
                    acc[m][n] = __builtin_amdgcn_mfma_f32_16x16x32_bf16(af, bf[n], acc[m][n], 0, 0, 0);
                    acc[m][n] = __builtin_amdgcn_mfma_f32_16x16x32_bf16(mf_, bf[n], acc[m][n], 0, 0, 0);
                    acc[m][n] = __builtin_amdgcn_mfma_f32_16x16x32_bf16(ef, bf[n], acc[m][n], 0, 0, 0);
                }
            }
        }
    }
    // epilogue: C = sB*acc + bias
#pragma unroll
    for (int n = 0; n < 4; ++n) {
        int col = col0 + wc * 64 + n * 16 + (l & 15);
        float bv = bias[col];
#pragma unroll
        for (int m = 0; m < 4; ++m) {
            int grow = row0 + wr * 64 + m * 16 + ((l >> 4) << 2);
#pragma unroll
            for (int r = 0; r < 4; ++r)
                Cm[(size_t)(grow + r) * Nn + col] = fmaf(sB, acc[m][n][r], bv);
        }
    }
}

// ---------------------------------------------------------------------------
// stage a 64(seq) x 64(d) tile of codes into XOR-swizzled LDS (pure copy).
// ---------------------------------------------------------------------------
__device__ __forceinline__ void stage_k_tile(const ushort* __restrict__ src,
                                             ushort* lds, int tid) {
    int row = tid >> 2, u0 = (tid & 3) << 1, r7 = row & 7;
    const ushort* p = src + (size_t)row * K3C + (u0 << 3);
    s16x8 t0 = *(const s16x8*)(p);
    s16x8 t1 = *(const s16x8*)(p + 8);
    *(s16x8*)(lds + row * 64 + ((u0 ^ r7) << 3)) = t0;
    *(s16x8*)(lds + row * 64 + (((u0 | 1) ^ r7) << 3)) = t1;
}

// stage a 64(seq) x 64(d) V tile TRANSPOSED into swizzled LDS: vt[d][j]
__device__ __forceinline__ void stage_vT_tile(const ushort* __restrict__ src,
                                              ushort* lds, int tid) {
    int d = tid >> 2, j0 = (tid & 3) << 4;
    const ushort* p = src + (size_t)j0 * K3C + d;
    s16x8 a, b;
#pragma unroll
    for (int jj = 0; jj < 8; ++jj) a[jj] = (short)p[(size_t)jj * K3C];
#pragma unroll
    for (int jj = 0; jj < 8; ++jj) b[jj] = (short)p[(size_t)(8 + jj) * K3C];
    int u0 = j0 >> 3, d7 = d & 7;
    *(s16x8*)(lds + d * 64 + ((u0 ^ d7) << 3)) = a;
    *(s16x8*)(lds + d * 64 + (((u0 | 1) ^ d7) << 3)) = b;
}

// ---------------------------------------------------------------------------
// pass A: global max |dot_int| (codes are the integer values; dot is exact)
// ---------------------------------------------------------------------------
__global__ __launch_bounds__(256) void attn_maxdot_kernel(const ushort* __restrict__ codes,
                                                          unsigned* __restrict__ umaxdot) {
    __shared__ ushort kt[64 * 64];
    __shared__ float red[4];
    int bh = blockIdx.y, b = bh / NH, h = bh % NH;
    int i0 = blockIdx.x * 64;
    int tid = threadIdx.x, l = tid & 63, w = tid >> 6;

    const ushort* qp = codes + (size_t)(b * NN + i0 + w * 16 + (l & 15)) * K3C + h * ND + ((l >> 4) << 3);
    s16x8 qf0 = *(const s16x8*)(qp);
    s16x8 qf1 = *(const s16x8*)(qp + 32);

    const ushort* kbase = codes + (size_t)(b * NN) * K3C + NC + h * ND;
    float md = 0.0f;
    for (int st = 0; st < NN / 64; ++st) {
        __syncthreads();
        stage_k_tile(kbase + (size_t)st * 64 * K3C, kt, tid);
        __syncthreads();
#pragma unroll
        for (int jt = 0; jt < 4; ++jt) {
            int row = (jt << 4) + (l & 15);
            f32x4 acc = {0.f, 0.f, 0.f, 0.f};
            s16x8 kf0 = *(s16x8*)(kt + row * 64 + ((((l >> 4)    ) ^ (row & 7)) << 3));
            s16x8 kf1 = *(s16x8*)(kt + row * 64 + ((((l >> 4) + 4) ^ (row & 7)) << 3));
            acc = __builtin_amdgcn_mfma_f32_16x16x32_bf16(qf0, kf0, acc, 0, 0, 0);
            acc = __builtin_amdgcn_mfma_f32_16x16x32_bf16(qf1, kf1, acc, 0, 0, 0);
#pragma unroll
            for (int r = 0; r < 4; ++r) md = fmaxf(md, fabsf(acc[r]));
        }
    }
    for (int m = 1; m < 64; m <<= 1) md = fmaxf(md, __shfl_xor(md, m, 64));
    if (l == 0) red[w] = md;
    __syncthreads();
    if (tid == 0)
        atomicMax(umaxdot, __float_as_uint(fmaxf(fmaxf(red[0], red[1]), fmaxf(red[2], red[3]))));
}

// ---------------------------------------------------------------------------
// fused log-int-softmax + PV.  -log2(p) = log2(U) - aq*log2e, U = sum exp(aq)
// ---------------------------------------------------------------------------
__global__ __launch_bounds__(256) void attn_fused_kernel(const ushort* __restrict__ codes,
                                                         const unsigned* __restrict__ uq,
                                                         const unsigned* __restrict__ umaxdot,
                                                         float* __restrict__ O) {
    __shared__ ushort kt[64 * 64];
    __shared__ ushort vt[64 * 64];
    __shared__ ushort ps[4][16 * 64];
    int bh = blockIdx.y, b = bh / NH, h = bh % NH;
    int i0 = blockIdx.x * 64;
    int tid = threadIdx.x, l = tid & 63, w = tid >> 6;
    float s = qsc(uq);
    float c = s * s * ATTN_SCALE;
    float sa = __uint_as_float(*umaxdot) * c / 127.0f + 1e-8f;   // s_attn
    float rr = c / sa;                                           // dot -> attn-code
    float kk = sa * 1.44269504088896340736f;                     // s_attn * log2(e)

    const ushort* qp = codes + (size_t)(b * NN + i0 + w * 16 + (l & 15)) * K3C + h * ND + ((l >> 4) << 3);
    s16x8 qf0 = *(const s16x8*)(qp);
    s16x8 qf1 = *(const s16x8*)(qp + 32);

    const ushort* kbase = codes + (size_t)(b * NN) * K3C + NC + h * ND;
    const ushort* vbase = codes + (size_t)(b * NN) * K3C + 2 * NC + h * ND;

    // ---- sweep 1: U[r] = sum_j exp(aq) per row ----
    float U[4] = {0.f, 0.f, 0.f, 0.f};
    for (int st = 0; st < NN / 64; ++st) {
        __syncthreads();
        stage_k_tile(kbase + (size_t)st * 64 * K3C, kt, tid);
        __syncthreads();
#pragma unroll
        for (int jt = 0; jt < 4; ++jt) {
            int row = (jt << 4) + (l & 15);
            f32x4 acc = {0.f, 0.f, 0.f, 0.f};
            s16x8 kf0 = *(s16x8*)(kt + row * 64 + ((((l >> 4)    ) ^ (row & 7)) << 3));
            s16x8 kf1 = *(s16x8*)(kt + row * 64 + ((((l >> 4) + 4) ^ (row & 7)) << 3));
            acc = __builtin_amdgcn_mfma_f32_16x16x32_bf16(qf0, kf0, acc, 0, 0, 0);
            acc = __builtin_amdgcn_mfma_f32_16x16x32_bf16(qf1, kf1, acc, 0, 0, 0);
#pragma unroll
            for (int r = 0; r < 4; ++r) {
                float m = rintf(acc[r] * rr);          // |dot*rr| < 127.0001 -> no clamp
                U[r] += exp2f(kk * m);
            }
        }
    }
#pragma unroll
    for (int r = 0; r < 4; ++r) {
        for (int msk = 1; msk < 16; msk <<= 1) U[r] += __shfl_xor(U[r], msk, 64);
    }
    float lu[4];
#pragma unroll
    for (int r = 0; r < 4; ++r) lu[r] = log2f(U[r]);

    // ---- sweep 2: recompute scores -> p = 2^-lg -> PV ----
    f32x4 oacc[4];
#pragma unroll
    for (int dt = 0; dt < 4; ++dt) oacc[dt] = (f32x4){0.f, 0.f, 0.f, 0.f};
    ushort* myps = (ushort*)ps[w];
    for (int st = 0; st < NN / 64; ++st) {
        __syncthreads();
        stage_k_tile(kbase + (size_t)st * 64 * K3C, kt, tid);
        stage_vT_tile(vbase + (size_t)st * 64 * K3C, vt, tid);
        __syncthreads();
#pragma unroll
        for (int jt = 0; jt < 4; ++jt) {
            int row = (jt << 4) + (l & 15);
            f32x4 acc = {0.f, 0.f, 0.f, 0.f};
            s16x8 kf0 = *(s16x8*)(kt + row * 64 + ((((l >> 4)    ) ^ (row & 7)) << 3));
            s16x8 kf1 = *(s16x8*)(kt + row * 64 + ((((l >> 4) + 4) ^ (row & 7)) << 3));
            acc = __builtin_amdgcn_mfma_f32_16x16x32_bf16(qf0, kf0, acc, 0, 0, 0);
            acc = __builtin_amdgcn_mfma_f32_16x16x32_bf16(qf1, kf1, acc, 0, 0, 0);
#pragma unroll
            for (int r = 0; r < 4; ++r) {
                float m = rintf(acc[r] * rr);
                float tt = lu[r] - kk * m;
                float lg = fminf(fmaxf(rintf(tt), 0.0f), 15.0f);
                int lgi = (int)lg;
                ushort pbits = (ushort)((127 - lgi) << 7);   // bf16 bits of 2^-lg
                int prow = ((l >> 4) << 2) + r;              // 0..15
                int j = (jt << 4) + (l & 15);                // 0..63
                int g = ((j >> 3) ^ (prow & 7)) ^ ((prow >> 3) << 2);
                myps[prow * 64 + (g << 3) + (j & 7)] = pbits;
            }
        }
        // PV: O[16 x 64] += P[16 x 64] * V[64 x 64]
#pragma unroll
        for (int kc = 0; kc < 2; ++kc) {
            int prow = l & 15;
            int gA = (((kc << 2) + (l >> 4)) ^ (prow & 7)) ^ ((prow >> 3) << 2);
            s16x8 pf = *(s16x8*)(myps + prow * 64 + (gA << 3));
#pragma unroll
            for (int dt = 0; dt < 4; ++dt) {
                int drow = (dt << 4) + (l & 15);
                s16x8 vf = *(s16x8*)(vt + drow * 64 + ((((kc << 2) + (l >> 4)) ^ (drow & 7)) << 3));
                oacc[dt] = __builtin_amdgcn_mfma_f32_16x16x32_bf16(pf, vf, oacc[dt], 0, 0, 0);
            }
        }
    }
    // write O (scale codes back by s_qkv)
#pragma unroll
    for (int dt = 0; dt < 4; ++dt)
#pragma unroll
        for (int r = 0; r < 4; ++r) {
            int orow = i0 + w * 16 + ((l >> 4) << 2) + r;
            O[(size_t)(b * NN + orow) * NC + h * ND + (dt << 4) + (l & 15)] = s * oacc[dt][r];
        }
}

// ---------------------------------------------------------------------------
// launch
// ---------------------------------------------------------------------------
extern "C" void kernel_launch(void* const* d_in, const int* in_sizes, int n_in,
                              void* d_out, int out_size, void* d_ws, size_t ws_size,
                              hipStream_t stream) {
    const float* x      = (const float*)d_in[0];
    const float* w_qkv  = (const float*)d_in[1];
    const float* b_qkv  = (const float*)d_in[2];
    const float* w_out  = (const float*)d_in[3];
    const float* b_out  = (const float*)d_in[4];
    float* out = (float*)d_out;

    // ---- workspace layout (proven 56.6 MB envelope, lifetime-overlapped) ----
    char* ws = (char*)d_ws;
    unsigned* u = (unsigned*)ws;                  // 0:wqkv 1:wout 2:qkv 3:maxdot 4:out
    const size_t qkvB = (size_t)ROWS * K3C * 4;            // 37.75 MB
    float*  qkv     = (float*)(ws + 256);                  // f32 qkv (live: gemm1..quantcodes)
    float*  out_tmp = (float*)(ws + 256);                  // gemm2 out (after qkv dead), 12.58 MB
    ushort* woc     = (ushort*)(ws + 256 + 16 * 1024 * 1024);  // w_out codes (after qkv dead)
    char*   codesRg = ws + 256 + qkvB;                     // 18.87 MB region
    ushort* codes   = (ushort*)codesRg;                    // qkv codes (quantcodes..attn_fused)
    ushort* xsplit  = (ushort*)codesRg;                    // 3-term split of x / O, 18.87 MB
    ushort* wqc     = (ushort*)d_out;                      // w_qkv codes staged in d_out (3.54 MB),
                                                           // dead before attn_fused writes O

    hipMemsetAsync(u, 0, 64, stream);

    // weight maxima + codes
    maxabs_kernel<<<512, 256, 0, stream>>>(w_qkv, (long long)K3C * NC, u + 0);
    maxabs_kernel<<<512, 256, 0, stream>>>(w_out, (long long)NC * NC, u + 1);
    quantcodes_kernel<<<512, 256, 0, stream>>>(w_qkv, wqc, (long long)K3C * NC, u + 0);

    // x -> 3-term split, then GEMM1: qkv = sW*(x @ n^T) + b_qkv
    split3_kernel<<<1024, 256, 0, stream>>>(x, xsplit, (long long)ROWS * NC);
    gemm3_mfma_kernel<<<dim3(K3C / 128, ROWS / 128), 256, 0, stream>>>(xsplit, wqc, b_qkv,
                                                                       qkv, K3C, u + 0);
    // qact_qkv -> codes (clobbers xsplit, dead)
    maxabs_kernel<<<1024, 256, 0, stream>>>(qkv, (long long)ROWS * K3C, u + 2);
    quantcodes_kernel<<<2048, 256, 0, stream>>>(qkv, codes, (long long)ROWS * K3C, u + 2);
    // w_out codes into dead qkv-f32 region (after quantcodes above)
    quantcodes_kernel<<<256, 256, 0, stream>>>(w_out, woc, (long long)NC * NC, u + 1);

    // attention (O f32 -> d_out; clobbers wqc, dead)
    attn_maxdot_kernel<<<dim3(NN / 64, NHEADS), 256, 0, stream>>>(codes, u + 3);
    attn_fused_kernel<<<dim3(NN / 64, NHEADS), 256, 0, stream>>>(codes, u + 2, u + 3, out);

    // O -> 3-term split (clobbers codes, dead), then GEMM2 -> out_tmp
    split3_kernel<<<1024, 256, 0, stream>>>(out, xsplit, (long long)ROWS * NC);
    gemm3_mfma_kernel<<<dim3(NC / 128, ROWS / 128), 256, 0, stream>>>(xsplit, woc, b_out,
                                                                      out_tmp, NC, u + 1);
    // qact_out -> d_out
    maxabs_kernel<<<1024, 256, 0, stream>>>(out_tmp, (long long)ROWS * NC, u + 4);
    quant_kernel<<<1024, 256, 0, stream>>>(out_tmp, out, (long long)ROWS * NC, u + 4);
}

// Round 6
// 363.139 us; speedup vs baseline: 4.9897x; 1.1682x over previous
//
#include <hip/hip_runtime.h>

// Problem constants
#define NB 2
#define NN 2048
#define NC 768
#define NH 12
#define ND 64
#define ROWS (NB * NN)      // 4096
#define K3C (3 * NC)        // 2304
#define NHEADS (NB * NH)    // 24
#define ATTN_SCALE 0.125f   // 64^-0.5

typedef __attribute__((ext_vector_type(8))) short s16x8;
typedef __attribute__((ext_vector_type(4))) float f32x4;
typedef __attribute__((ext_vector_type(2))) unsigned int u32x2;

// ---------------------------------------------------------------------------
// helpers
// ---------------------------------------------------------------------------
__device__ __forceinline__ float qsc(const unsigned* u) {
    return __uint_as_float(*u) / 127.0f + 1e-8f;   // s = max|t|/127 + 1e-8
}
__device__ __forceinline__ float fq(float t, float s) {
    return fminf(fmaxf(rintf(t / s), -127.0f), 127.0f) * s;
}
__device__ __forceinline__ float qcode(float t, float s) {   // integer code as f32 (exact div)
    return fminf(fmaxf(rintf(t / s), -127.0f), 127.0f);
}
__device__ __forceinline__ short bfbits(float f) {           // exact for ints<=127 & pow2
    return (short)(__float_as_uint(f) >> 16);
}
__device__ __forceinline__ ushort bf_rne(float x) {          // round-to-nearest-even bf16
    unsigned u = __float_as_uint(x);
    return (ushort)((u + 0x7fffu + ((u >> 16) & 1u)) >> 16);
}

// ---------------------------------------------------------------------------
// max |x| reduction (weights only now)
// ---------------------------------------------------------------------------
__global__ __launch_bounds__(256) void maxabs_kernel(const float* __restrict__ x,
                                                     long long n, unsigned* out) {
    float m = 0.0f;
    long long stride4 = (long long)gridDim.x * blockDim.x * 4;
    for (long long j = ((long long)blockIdx.x * blockDim.x + threadIdx.x) * 4; j < n; j += stride4) {
        float4 v = *(const float4*)(x + j);
        m = fmaxf(m, fmaxf(fmaxf(fabsf(v.x), fabsf(v.y)), fmaxf(fabsf(v.z), fabsf(v.w))));
    }
    for (int off = 32; off > 0; off >>= 1) m = fmaxf(m, __shfl_down(m, off, 64));
    __shared__ float sm[4];
    int lane = threadIdx.x & 63, w = threadIdx.x >> 6;
    if (lane == 0) sm[w] = m;
    __syncthreads();
    if (threadIdx.x == 0) {
        float mm = fmaxf(fmaxf(sm[0], sm[1]), fmaxf(sm[2], sm[3]));
        atomicMax(out, __float_as_uint(mm));
    }
}

// ---------------------------------------------------------------------------
// elementwise fake-quant
// ---------------------------------------------------------------------------
__global__ __launch_bounds__(256) void quant_kernel(const float* in, float* out,
                                                    long long n, const unsigned* umax) {
    float s = qsc(umax);
    long long stride4 = (long long)gridDim.x * blockDim.x * 4;
    for (long long j = ((long long)blockIdx.x * blockDim.x + threadIdx.x) * 4; j < n; j += stride4) {
        float4 v = *(const float4*)(in + j);
        v.x = fq(v.x, s); v.y = fq(v.y, s); v.z = fq(v.z, s); v.w = fq(v.w, s);
        *(float4*)(out + j) = v;
    }
}

// ---------------------------------------------------------------------------
// f32 -> integer codes stored as bf16 bits (exact division, bit-identical
// to the reference's quant decisions). codes are ints in [-127,127].
// ---------------------------------------------------------------------------
__global__ __launch_bounds__(256) void quantcodes_kernel(const float* __restrict__ in,
                                                         ushort* __restrict__ codes,
                                                         long long n,
                                                         const unsigned* __restrict__ umax) {
    float s = qsc(umax);
    long long stride8 = (long long)gridDim.x * blockDim.x * 8;
    for (long long j = ((long long)blockIdx.x * blockDim.x + threadIdx.x) * 8; j < n; j += stride8) {
        float4 a = *(const float4*)(in + j);
        float4 b = *(const float4*)(in + j + 4);
        s16x8 o;
        o[0] = bfbits(qcode(a.x, s)); o[1] = bfbits(qcode(a.y, s));
        o[2] = bfbits(qcode(a.z, s)); o[3] = bfbits(qcode(a.w, s));
        o[4] = bfbits(qcode(b.x, s)); o[5] = bfbits(qcode(b.y, s));
        o[6] = bfbits(qcode(b.z, s)); o[7] = bfbits(qcode(b.w, s));
        *(s16x8*)(codes + j) = o;
    }
}

// ---------------------------------------------------------------------------
// f32 [R][768] -> 3-term bf16 split stored [R][2304]: hi | mid | lo planes.
// ---------------------------------------------------------------------------
__global__ __launch_bounds__(256) void split3_kernel(const float* __restrict__ in,
                                                     ushort* __restrict__ xs,
                                                     long long n) {
    long long stride8 = (long long)gridDim.x * blockDim.x * 8;
    for (long long j = ((long long)blockIdx.x * blockDim.x + threadIdx.x) * 8; j < n; j += stride8) {
        long long row = j / NC, col = j % NC;
        s16x8 h, m, l;
#pragma unroll
        for (int i = 0; i < 8; i += 4) {
            float4 v = *(const float4*)(in + j + i);
            float vv[4] = {v.x, v.y, v.z, v.w};
#pragma unroll
            for (int t = 0; t < 4; ++t) {
                ushort hb = bf_rne(vv[t]);
                float hf = __uint_as_float(((unsigned)hb) << 16);
                float r1 = vv[t] - hf;
                ushort mb = bf_rne(r1);
                float mf = __uint_as_float(((unsigned)mb) << 16);
                h[i + t] = (short)hb;
                m[i + t] = (short)mb;
                l[i + t] = (short)bf_rne(r1 - mf);
            }
        }
        ushort* dst = xs + row * (3 * NC) + col;
        *(s16x8*)(dst) = h;
        *(s16x8*)(dst + NC) = m;
        *(s16x8*)(dst + 2 * NC) = l;
    }
}

// ---------------------------------------------------------------------------
// MFMA GEMM: C[i,j] = sB * sum_k (hi+mid+lo)_ik * n_jk + bias[j]
// + fused maxabs of C into uC (saves a full re-read pass).
// ---------------------------------------------------------------------------
__global__ __launch_bounds__(256) void gemm3_mfma_kernel(const ushort* __restrict__ As,
                                                         const ushort* __restrict__ Bc,
                                                         const float* __restrict__ bias,
                                                         float* __restrict__ Cm, int Nn,
                                                         const unsigned* __restrict__ uB,
                                                         unsigned* __restrict__ uC) {
    __shared__ ushort ah[128 * 64], am[128 * 64], al[128 * 64], bs[128 * 64];
    __shared__ float redmx[4];
    const float sB = qsc(uB);
    const int tid = threadIdx.x, l = tid & 63, w = tid >> 6;
    const int row0 = blockIdx.y * 128, col0 = blockIdx.x * 128;
    const int wr = w >> 1, wc = w & 1;
    f32x4 acc[4][4];
#pragma unroll
    for (int m = 0; m < 4; ++m)
#pragma unroll
        for (int n = 0; n < 4; ++n) acc[m][n] = (f32x4){0.f, 0.f, 0.f, 0.f};

    const int sr = tid >> 1, sh = (tid & 1) << 5;   // stage: row 0..127, k-off 0/32
    const int su = sh >> 3, s7 = sr & 7;

    for (int k0 = 0; k0 < NC; k0 += 64) {
        __syncthreads();
        {   // A hi/mid/lo tiles
            const ushort* ph = As + (size_t)(row0 + sr) * (3 * NC) + k0 + sh;
            ushort* dsts[3] = {ah + sr * 64, am + sr * 64, al + sr * 64};
#pragma unroll
            for (int pl = 0; pl < 3; ++pl) {
                const ushort* p = ph + pl * NC;
                s16x8 t0 = *(const s16x8*)(p),      t1 = *(const s16x8*)(p + 8);
                s16x8 t2 = *(const s16x8*)(p + 16), t3 = *(const s16x8*)(p + 24);
                ushort* d = dsts[pl];
                *(s16x8*)(d + (((su | 0) ^ s7) << 3)) = t0;
                *(s16x8*)(d + (((su | 1) ^ s7) << 3)) = t1;
                *(s16x8*)(d + (((su | 2) ^ s7) << 3)) = t2;
                *(s16x8*)(d + (((su | 3) ^ s7) << 3)) = t3;
            }
            // B tile
            const ushort* pb = Bc + (size_t)(col0 + sr) * NC + k0 + sh;
            s16x8 b0 = *(const s16x8*)(pb),      b1 = *(const s16x8*)(pb + 8);
            s16x8 b2 = *(const s16x8*)(pb + 16), b3 = *(const s16x8*)(pb + 24);
            ushort* brow = bs + sr * 64;
            *(s16x8*)(brow + (((su | 0) ^ s7) << 3)) = b0;
            *(s16x8*)(brow + (((su | 1) ^ s7) << 3)) = b1;
            *(s16x8*)(brow + (((su | 2) ^ s7) << 3)) = b2;
            *(s16x8*)(brow + (((su | 3) ^ s7) << 3)) = b3;
        }
        __syncthreads();
#pragma unroll
        for (int ks = 0; ks < 2; ++ks) {
            s16x8 bf[4];
#pragma unroll
            for (int n = 0; n < 4; ++n) {
                int br = wc * 64 + n * 16 + (l & 15);
                bf[n] = *(s16x8*)(bs + br * 64 + ((((ks << 2) + (l >> 4)) ^ (br & 7)) << 3));
            }
#pragma unroll
            for (int m = 0; m < 4; ++m) {
                int ar = wr * 64 + m * 16 + (l & 15);
                int ao = ar * 64 + ((((ks << 2) + (l >> 4)) ^ (ar & 7)) << 3);
                s16x8 af = *(s16x8*)(ah + ao);
                s16x8 mf_ = *(s16x8*)(am + ao);
                s16x8 ef = *(s16x8*)(al + ao);
#pragma unroll
                for (int n = 0; n < 4; ++n) {
                    acc[m][n] = __builtin_amdgcn_mfma_f32_16x16x32_bf16(af, bf[n], acc[m][n], 0, 0, 0);
                    acc[m][n] = __builtin_amdgcn_mfma_f32_16x16x32_bf16(mf_, bf[n], acc[m][n], 0, 0, 0);
                    acc[m][n] = __builtin_amdgcn_mfma_f32_16x16x32_bf16(ef, bf[n], acc[m][n], 0, 0, 0);
                }
            }
        }
    }
    // epilogue: C = sB*acc + bias, fused max|C|
    float mx = 0.0f;
#pragma unroll
    for (int n = 0; n < 4; ++n) {
        int col = col0 + wc * 64 + n * 16 + (l & 15);
        float bv = bias[col];
#pragma unroll
        for (int m = 0; m < 4; ++m) {
            int grow = row0 + wr * 64 + m * 16 + ((l >> 4) << 2);
#pragma unroll
            for (int r = 0; r < 4; ++r) {
                float v = fmaf(sB, acc[m][n][r], bv);
                Cm[(size_t)(grow + r) * Nn + col] = v;
                mx = fmaxf(mx, fabsf(v));
            }
        }
    }
    for (int msk = 1; msk < 64; msk <<= 1) mx = fmaxf(mx, __shfl_xor(mx, msk, 64));
    if (l == 0) redmx[w] = mx;
    __syncthreads();
    if (tid == 0)
        atomicMax(uC, __float_as_uint(fmaxf(fmaxf(redmx[0], redmx[1]), fmaxf(redmx[2], redmx[3]))));
}

// ---------------------------------------------------------------------------
// stage a 64(seq) x 64(d) tile of codes into XOR-swizzled LDS (pure copy).
// ---------------------------------------------------------------------------
__device__ __forceinline__ void stage_k_tile(const ushort* __restrict__ src,
                                             ushort* lds, int tid) {
    int row = tid >> 2, u0 = (tid & 3) << 1, r7 = row & 7;
    const ushort* p = src + (size_t)row * K3C + (u0 << 3);
    s16x8 t0 = *(const s16x8*)(p);
    s16x8 t1 = *(const s16x8*)(p + 8);
    *(s16x8*)(lds + row * 64 + ((u0 ^ r7) << 3)) = t0;
    *(s16x8*)(lds + row * 64 + (((u0 | 1) ^ r7) << 3)) = t1;
}

// stage a 64(seq) x 64(d) V tile TRANSPOSED into swizzled LDS: vt[d][j].
// Coalesced 16B global loads + scalar LDS scatter (replaces 16 scattered
// global u16 loads per lane).
__device__ __forceinline__ void stage_vT_tile(const ushort* __restrict__ src,
                                              ushort* lds, int tid) {
    int j = tid >> 2, d0 = (tid & 3) << 4;
    const ushort* p = src + (size_t)j * K3C + d0;
    s16x8 a = *(const s16x8*)(p);
    s16x8 b = *(const s16x8*)(p + 8);
    int jo = j >> 3, jl = j & 7;
#pragma unroll
    for (int t = 0; t < 8; ++t) {
        int d = d0 + t;
        lds[d * 64 + ((jo ^ (d & 7)) << 3) + jl] = (ushort)a[t];
    }
#pragma unroll
    for (int t = 0; t < 8; ++t) {
        int d = d0 + 8 + t;
        lds[d * 64 + ((jo ^ (d & 7)) << 3) + jl] = (ushort)b[t];
    }
}

// ---------------------------------------------------------------------------
// pass A: global max |dot_int|. mfma(K,Q) (operand swap; same fragments).
// ---------------------------------------------------------------------------
__global__ __launch_bounds__(256) void attn_maxdot_kernel(const ushort* __restrict__ codes,
                                                          unsigned* __restrict__ umaxdot) {
    __shared__ ushort kt[64 * 64];
    __shared__ float red[4];
    int bh = blockIdx.y, b = bh / NH, h = bh % NH;
    int i0 = blockIdx.x * 64;
    int tid = threadIdx.x, l = tid & 63, w = tid >> 6;
    int qr = l & 15, g = l >> 4;

    const ushort* qp = codes + (size_t)(b * NN + i0 + w * 16 + qr) * K3C + h * ND + (g << 3);
    s16x8 qf0 = *(const s16x8*)(qp);
    s16x8 qf1 = *(const s16x8*)(qp + 32);

    const ushort* kbase = codes + (size_t)(b * NN) * K3C + NC + h * ND;
    float md = 0.0f;
    for (int st = 0; st < NN / 64; ++st) {
        __syncthreads();
        stage_k_tile(kbase + (size_t)st * 64 * K3C, kt, tid);
        __syncthreads();
#pragma unroll
        for (int jt = 0; jt < 4; ++jt) {
            int row = (jt << 4) + qr;
            f32x4 acc = {0.f, 0.f, 0.f, 0.f};
            s16x8 kf0 = *(s16x8*)(kt + row * 64 + (((g    ) ^ (row & 7)) << 3));
            s16x8 kf1 = *(s16x8*)(kt + row * 64 + (((g + 4) ^ (row & 7)) << 3));
            acc = __builtin_amdgcn_mfma_f32_16x16x32_bf16(kf0, qf0, acc, 0, 0, 0);
            acc = __builtin_amdgcn_mfma_f32_16x16x32_bf16(kf1, qf1, acc, 0, 0, 0);
#pragma unroll
            for (int r = 0; r < 4; ++r) md = fmaxf(md, fabsf(acc[r]));
        }
    }
    for (int m = 1; m < 64; m <<= 1) md = fmaxf(md, __shfl_xor(md, m, 64));
    if (l == 0) red[w] = md;
    __syncthreads();
    if (tid == 0)
        atomicMax(umaxdot, __float_as_uint(fmaxf(fmaxf(red[0], red[1]), fmaxf(red[2], red[3]))));
}

// ---------------------------------------------------------------------------
// fused log-int-softmax + PV with swapped QK^T: lane holds one q-row's
// score-columns -> scalar U/lu per lane, packed b64 P writes.
// ---------------------------------------------------------------------------
__global__ __launch_bounds__(256) void attn_fused_kernel(const ushort* __restrict__ codes,
                                                         const unsigned* __restrict__ uq,
                                                         const unsigned* __restrict__ umaxdot,
                                                         float* __restrict__ O) {
    __shared__ ushort kt[64 * 64];
    __shared__ ushort vt[64 * 64];
    __shared__ ushort ps[4][16 * 64];
    int bh = blockIdx.y, b = bh / NH, h = bh % NH;
    int i0 = blockIdx.x * 64;
    int tid = threadIdx.x, l = tid & 63, w = tid >> 6;
    int qr = l & 15, g = l >> 4;
    float s = qsc(uq);
    float cf = s * s * ATTN_SCALE;
    float sa = __uint_as_float(*umaxdot) * cf / 127.0f + 1e-8f;  // s_attn
    float rr = cf / sa;                                          // dot -> attn-code
    float kk = sa * 1.44269504088896340736f;                     // s_attn * log2(e)

    const ushort* qp = codes + (size_t)(b * NN + i0 + w * 16 + qr) * K3C + h * ND + (g << 3);
    s16x8 qf0 = *(const s16x8*)(qp);
    s16x8 qf1 = *(const s16x8*)(qp + 32);

    const ushort* kbase = codes + (size_t)(b * NN) * K3C + NC + h * ND;
    const ushort* vbase = codes + (size_t)(b * NN) * K3C + 2 * NC + h * ND;

    // ---- sweep 1: U = sum_j exp(aq) for q-row qr ----
    float U = 0.0f;
    for (int st = 0; st < NN / 64; ++st) {
        __syncthreads();
        stage_k_tile(kbase + (size_t)st * 64 * K3C, kt, tid);
        __syncthreads();
#pragma unroll
        for (int jt = 0; jt < 4; ++jt) {
            int row = (jt << 4) + qr;
            f32x4 acc = {0.f, 0.f, 0.f, 0.f};
            s16x8 kf0 = *(s16x8*)(kt + row * 64 + (((g    ) ^ (row & 7)) << 3));
            s16x8 kf1 = *(s16x8*)(kt + row * 64 + (((g + 4) ^ (row & 7)) << 3));
            acc = __builtin_amdgcn_mfma_f32_16x16x32_bf16(kf0, qf0, acc, 0, 0, 0);
            acc = __builtin_amdgcn_mfma_f32_16x16x32_bf16(kf1, qf1, acc, 0, 0, 0);
#pragma unroll
            for (int r = 0; r < 4; ++r) {
                float m = rintf(acc[r] * rr);          // |dot*rr| < 127.0001 -> no clamp
                U += exp2f(kk * m);
            }
        }
    }
    U += __shfl_xor(U, 16, 64);
    U += __shfl_xor(U, 32, 64);
    float lu = log2f(U);

    // ---- sweep 2: scores -> packed pbits -> PV ----
    f32x4 oacc[4];
#pragma unroll
    for (int dt = 0; dt < 4; ++dt) oacc[dt] = (f32x4){0.f, 0.f, 0.f, 0.f};
    ushort* myps = (ushort*)ps[w];
    for (int st = 0; st < NN / 64; ++st) {
        __syncthreads();
        stage_k_tile(kbase + (size_t)st * 64 * K3C, kt, tid);
        stage_vT_tile(vbase + (size_t)st * 64 * K3C, vt, tid);
        __syncthreads();
#pragma unroll
        for (int jt = 0; jt < 4; ++jt) {
            int row = (jt << 4) + qr;
            f32x4 acc = {0.f, 0.f, 0.f, 0.f};
            s16x8 kf0 = *(s16x8*)(kt + row * 64 + (((g    ) ^ (row & 7)) << 3));
            s16x8 kf1 = *(s16x8*)(kt + row * 64 + (((g + 4) ^ (row & 7)) << 3));
            acc = __builtin_amdgcn_mfma_f32_16x16x32_bf16(kf0, qf0, acc, 0, 0, 0);
            acc = __builtin_amdgcn_mfma_f32_16x16x32_bf16(kf1, qf1, acc, 0, 0, 0);
            int lg[4];
#pragma unroll
            for (int r = 0; r < 4; ++r) {
                float m = rintf(acc[r] * rr);
                float tt = lu - kk * m;
                lg[r] = (int)fminf(fmaxf(rintf(tt), 0.0f), 15.0f);
            }
            unsigned w0 = (unsigned)(((127 - lg[0]) << 7) | ((127 - lg[1]) << 23));
            unsigned w1 = (unsigned)(((127 - lg[2]) << 7) | ((127 - lg[3]) << 23));
            // P[qr][16jt + 4g + r], 8-ushort-granule XOR swizzle on row qr
            int off = qr * 64 + (((jt << 4) + ((g >> 1) << 3)) ^ ((qr & 7) << 3)) + ((g & 1) << 2);
            *(u32x2*)(myps + off) = (u32x2){w0, w1};
        }
        // PV: O[16 x 64] += P[16 x 64] * V[64 x 64]
#pragma unroll
        for (int kc = 0; kc < 2; ++kc) {
            int poff = qr * 64 + (((kc << 5) + (g << 3)) ^ ((qr & 7) << 3));
            s16x8 pf = *(s16x8*)(myps + poff);
#pragma unroll
            for (int dt = 0; dt < 4; ++dt) {
                int drow = (dt << 4) + qr;
                s16x8 vf = *(s16x8*)(vt + drow * 64 + ((((kc << 2) + g) ^ (drow & 7)) << 3));
                oacc[dt] = __builtin_amdgcn_mfma_f32_16x16x32_bf16(pf, vf, oacc[dt], 0, 0, 0);
            }
        }
    }
    // write O (scale codes back by s_qkv)
#pragma unroll
    for (int dt = 0; dt < 4; ++dt)
#pragma unroll
        for (int r = 0; r < 4; ++r) {
            int orow = i0 + w * 16 + (g << 2) + r;
            O[(size_t)(b * NN + orow) * NC + h * ND + (dt << 4) + qr] = s * oacc[dt][r];
        }
}

// ---------------------------------------------------------------------------
// launch
// ---------------------------------------------------------------------------
extern "C" void kernel_launch(void* const* d_in, const int* in_sizes, int n_in,
                              void* d_out, int out_size, void* d_ws, size_t ws_size,
                              hipStream_t stream) {
    const float* x      = (const float*)d_in[0];
    const float* w_qkv  = (const float*)d_in[1];
    const float* b_qkv  = (const float*)d_in[2];
    const float* w_out  = (const float*)d_in[3];
    const float* b_out  = (const float*)d_in[4];
    float* out = (float*)d_out;

    // ---- workspace layout (proven 56.6 MB envelope, lifetime-overlapped) ----
    char* ws = (char*)d_ws;
    unsigned* u = (unsigned*)ws;                  // 0:wqkv 1:wout 2:qkv 3:maxdot 4:out
    const size_t qkvB = (size_t)ROWS * K3C * 4;            // 37.75 MB
    float*  qkv     = (float*)(ws + 256);                  // f32 qkv (live: gemm1..quantcodes)
    float*  out_tmp = (float*)(ws + 256);                  // gemm2 out (after qkv dead)
    ushort* woc     = (ushort*)(ws + 256 + 16 * 1024 * 1024);  // w_out codes (after qkv dead)
    char*   codesRg = ws + 256 + qkvB;                     // 18.87 MB region
    ushort* codes   = (ushort*)codesRg;                    // qkv codes (quantcodes..attn_fused)
    ushort* xsplit  = (ushort*)codesRg;                    // 3-term split of x / O
    ushort* wqc     = (ushort*)d_out;                      // w_qkv codes staged in d_out,
                                                           // dead before attn_fused writes O

    hipMemsetAsync(u, 0, 64, stream);

    // weight maxima + codes
    maxabs_kernel<<<512, 256, 0, stream>>>(w_qkv, (long long)K3C * NC, u + 0);
    maxabs_kernel<<<512, 256, 0, stream>>>(w_out, (long long)NC * NC, u + 1);
    quantcodes_kernel<<<512, 256, 0, stream>>>(w_qkv, wqc, (long long)K3C * NC, u + 0);

    // x -> 3-term split, then GEMM1 (fused maxabs of qkv -> u+2)
    split3_kernel<<<1024, 256, 0, stream>>>(x, xsplit, (long long)ROWS * NC);
    gemm3_mfma_kernel<<<dim3(K3C / 128, ROWS / 128), 256, 0, stream>>>(xsplit, wqc, b_qkv,
                                                                       qkv, K3C, u + 0, u + 2);
    // qact_qkv -> codes (clobbers xsplit, dead)
    quantcodes_kernel<<<2048, 256, 0, stream>>>(qkv, codes, (long long)ROWS * K3C, u + 2);
    // w_out codes into dead qkv-f32 region (after quantcodes above)
    quantcodes_kernel<<<256, 256, 0, stream>>>(w_out, woc, (long long)NC * NC, u + 1);

    // attention (O f32 -> d_out; clobbers wqc, dead)
    attn_maxdot_kernel<<<dim3(NN / 64, NHEADS), 256, 0, stream>>>(codes, u + 3);
    attn_fused_kernel<<<dim3(NN / 64, NHEADS), 256, 0, stream>>>(codes, u + 2, u + 3, out);

    // O -> 3-term split (clobbers codes, dead), then GEMM2 (fused maxabs -> u+4)
    split3_kernel<<<1024, 256, 0, stream>>>(out, xsplit, (long long)ROWS * NC);
    gemm3_mfma_kernel<<<dim3(NC / 128, ROWS / 128), 256, 0, stream>>>(xsplit, woc, b_out,
                                                                      out_tmp, NC, u + 1, u + 4);
    // qact_out -> d_out
    quant_kernel<<<1024, 256, 0, stream>>>(out_tmp, out, (long long)ROWS * NC, u + 4);
}